// Round 13
// baseline (167.075 us; speedup 1.0000x reference)
//
#include <hip/hip_runtime.h>
#include <hip/hip_bf16.h>

// ---- geometry (fixed by the problem) ----
#define CDIM 768
#define NHEAD 12
#define EDIM 64
#define TDIM 8
#define SDIM 576
#define NROW 16          // B*T
#define MDIM 9216        // NROW*SDIM
#define QKVN 2304

typedef __attribute__((ext_vector_type(4))) float f32x4;
typedef __bf16 bf16x8 __attribute__((ext_vector_type(8)));
typedef unsigned short u16;
typedef __attribute__((ext_vector_type(8))) unsigned short u16x8;

__device__ inline float bf2f(u16 u) {
  union { unsigned int i; float f; } x; x.i = ((unsigned int)u) << 16; return x.f;
}
__device__ inline u16 f2bf(float f) {
  union { float f; unsigned int i; } x; x.f = f;
  unsigned int i = x.i;
  return (u16)((i + 0x7FFFu + ((i >> 16) & 1u)) >> 16);
}
__device__ inline unsigned cvt_pk_bf16(float lo, float hi) {
  unsigned r;
  asm("v_cvt_pk_bf16_f32 %0, %1, %2" : "=v"(r) : "v"(lo), "v"(hi));
  return r;
}

// ---------------- cs = cond @ norm_w^T + 1  (2 x 768) ----------------
__global__ __launch_bounds__(256) void cs_kernel(const float* __restrict__ cond,
                                                 const float* __restrict__ nw,
                                                 float* __restrict__ cs) {
  int idx = blockIdx.x * 256 + threadIdx.x;      // 0..1535
  int b = idx / CDIM, c = idx % CDIM;
  const float* cr = cond + (size_t)b * CDIM;
  const float* wr = nw + (size_t)c * CDIM;
  float s = 1.0f;
  for (int j = 0; j < CDIM; j += 4) {
    float4 a = *(const float4*)(cr + j);
    float4 w = *(const float4*)(wr + j);
    s = fmaf(a.x, w.x, s); s = fmaf(a.y, w.y, s);
    s = fmaf(a.z, w.z, s); s = fmaf(a.w, w.w, s);
  }
  cs[idx] = s;
}

// ---------------- RMS-norm * cs -> xn (M, C) bf16, one-pass via LDS ----------------
__global__ __launch_bounds__(256) void norm_kernel(const float* __restrict__ x,
                                                   const float* __restrict__ cs,
                                                   u16* __restrict__ xn) {
  __shared__ float xs[16][772];
  __shared__ float red[16][17];
  __shared__ float rfac[16];
  int n = blockIdx.y;
  int hw0 = blockIdx.x * 16;
  int b = n >> 3, t = n & 7;
  int tx = threadIdx.x, ty = threadIdx.y;
  const float* xb = x + ((size_t)b * CDIM * TDIM + t) * SDIM;
  float acc = 0.0f;
  for (int c = ty; c < CDIM; c += 16) {
    float v = xb[(size_t)c * (TDIM * SDIM) + hw0 + tx];
    xs[tx][c] = v;
    acc = fmaf(v, v, acc);
  }
  red[ty][tx] = acc;
  __syncthreads();
  if (ty == 0) {
    float s = 0.0f;
    #pragma unroll
    for (int j = 0; j < 16; j++) s += red[j][tx];
    rfac[tx] = rsqrtf(s * (1.0f / (float)CDIM) + 1e-6f);
  }
  __syncthreads();
  const float* csb = cs + (size_t)b * CDIM;
  int flat = ty * 16 + tx;
  #pragma unroll
  for (int i = 0; i < 6; i++) {
    int idx = i * 256 + flat;
    int row = idx / 96;
    int cseg = idx - row * 96;
    int c0 = cseg * 8;
    float rf = rfac[row];
    float4 a0 = *(const float4*)&xs[row][c0];
    float4 a1 = *(const float4*)&xs[row][c0 + 4];
    float4 w0 = *(const float4*)(csb + c0);
    float4 w1 = *(const float4*)(csb + c0 + 4);
    u16x8 ov;
    ov[0] = f2bf(a0.x * w0.x * rf); ov[1] = f2bf(a0.y * w0.y * rf);
    ov[2] = f2bf(a0.z * w0.z * rf); ov[3] = f2bf(a0.w * w0.w * rf);
    ov[4] = f2bf(a1.x * w1.x * rf); ov[5] = f2bf(a1.y * w1.y * rf);
    ov[6] = f2bf(a1.z * w1.z * rf); ov[7] = f2bf(a1.w * w1.w * rf);
    *(u16x8*)(xn + ((size_t)n * SDIM + hw0 + row) * CDIM + c0) = ov;
  }
}

// ---------------- f32 -> bf16 weight convert ----------------
__global__ __launch_bounds__(256) void convert_kernel(const float* __restrict__ src,
                                                      u16* __restrict__ dst, int count4) {
  int i = blockIdx.x * 256 + threadIdx.x;
  if (i < count4) {
    float4 v = *(const float4*)(src + (size_t)i * 4);
    u16* d = dst + (size_t)i * 4;
    d[0] = f2bf(v.x); d[1] = f2bf(v.y); d[2] = f2bf(v.z); d[3] = f2bf(v.w);
  }
}

// ---------------- MFMA GEMM core: dbuf + counted vmcnt ----------------
__device__ __forceinline__ void gemm_bt_lds(const u16* __restrict__ A,
                                            const u16* __restrict__ B,
                                            int K, int m0, int n0, int tid,
                                            u16* ldsA, u16* ldsB,
                                            f32x4 acc[4][4]) {
  int lane = tid & 63;
  int wid = tid >> 6;
  int wm = (wid >> 1) * 64, wn = (wid & 1) * 64;
  int lr = lane & 15, lg = lane >> 4;
  const u16* gA = A + (size_t)(m0 + wid * 32 + (lane >> 3)) * K + (((lane & 7) ^ (lane >> 3)) * 8);
  const u16* gB = B + (size_t)(n0 + wid * 32 + (lane >> 3)) * K + (((lane & 7) ^ (lane >> 3)) * 8);
  u16* dA = ldsA + wid * 2048;
  u16* dB = ldsB + wid * 2048;
  auto STAGE = [&](int buf, int k0) {
    u16* dAb = dA + buf * 8192;
    u16* dBb = dB + buf * 8192;
    #pragma unroll
    for (int is = 0; is < 4; is++) {
      __builtin_amdgcn_global_load_lds(
          (const __attribute__((address_space(1))) unsigned int*)(gA + (size_t)(is * 8) * K + k0),
          (__attribute__((address_space(3))) unsigned int*)(dAb + is * 512),
          16, 0, 0);
      __builtin_amdgcn_global_load_lds(
          (const __attribute__((address_space(1))) unsigned int*)(gB + (size_t)(is * 8) * K + k0),
          (__attribute__((address_space(3))) unsigned int*)(dBb + is * 512),
          16, 0, 0);
    }
  };
  int nt = K >> 6;
  STAGE(0, 0);
  int cur = 0;
  #pragma unroll 1
  for (int t = 0; t < nt; t++) {
    if (t + 1 < nt) {
      STAGE(cur ^ 1, (t + 1) * 64);
      asm volatile("s_waitcnt vmcnt(8)" ::: "memory");
    } else {
      asm volatile("s_waitcnt vmcnt(0)" ::: "memory");
    }
    __builtin_amdgcn_s_barrier();
    __builtin_amdgcn_sched_barrier(0);
    const u16* lA = ldsA + cur * 8192;
    const u16* lB = ldsB + cur * 8192;
    #pragma unroll
    for (int kk = 0; kk < 2; kk++) {
      bf16x8 af[4], bfr[4];
      #pragma unroll
      for (int i = 0; i < 4; i++)
        af[i]  = *(const bf16x8*)&lA[(wm + i * 16 + lr) * 64 + (((lg + 4 * kk) ^ (lr & 7)) * 8)];
      #pragma unroll
      for (int j = 0; j < 4; j++)
        bfr[j] = *(const bf16x8*)&lB[(wn + j * 16 + lr) * 64 + (((lg + 4 * kk) ^ (lr & 7)) * 8)];
      #pragma unroll
      for (int i = 0; i < 4; i++)
        #pragma unroll
        for (int j = 0; j < 4; j++)
          acc[i][j] = __builtin_amdgcn_mfma_f32_16x16x32_bf16(af[i], bfr[j], acc[i][j], 0, 0, 0);
    }
    __builtin_amdgcn_sched_barrier(0);
    __builtin_amdgcn_s_barrier();
    __builtin_amdgcn_sched_barrier(0);
    cur ^= 1;
  }
}

// XCD-chunk swizzle: grid = 8 XCD * 9 m-blocks * NBLK n-blocks (bijective).
__device__ __forceinline__ void swz_tile(int L, int& m0, int& n0) {
  int xcd = L & 7, loc = L >> 3;
  int nblk = loc / 9, mloc = loc - nblk * 9;
  m0 = (xcd * 9 + mloc) * 128;
  n0 = nblk * 128;
}

// ---------------- QKV GEMM: fused cos-norm+RoPE, COALESCED LDS-staged stores ----------
__global__ __launch_bounds__(256) void gemm_qkv(const u16* __restrict__ xn,
                                                const u16* __restrict__ wq,
                                                const float* __restrict__ pos,
                                                const float* __restrict__ freqs,
                                                const float* __restrict__ scale,
                                                u16* __restrict__ q,
                                                u16* __restrict__ k,
                                                u16* __restrict__ vt) {
  __shared__ u16 smem[32768];              // 64 KB: staging dbuf; reused by epilogue
  u16* ldsA = smem;
  u16* ldsB = smem + 16384;
  f32x4 acc[4][4] = {};
  int tid = threadIdx.x;
  int m0, n0;
  swz_tile(blockIdx.x, m0, n0);
  gemm_bt_lds(xn, wq, CDIM, m0, n0, tid, ldsA, ldsB, acc);
  int lane = tid & 63, wid = tid >> 6;
  int wm = (wid >> 1) * 64, wn = (wid & 1) * 64;
  int lr = lane & 15, rb = (lane >> 4) * 4;
  int part = n0 / CDIM;                    // block-uniform
  int hbase = (n0 - part * CDIM) >> 6;     // block-uniform head base (2 heads/block)
  u16* T = smem;                           // [128][136]
  if (part < 2) {
    int h = hbase + (wn >> 6);             // wave-uniform head
    float fr = freqs[h * 8 + (lr & 7)];
    float sq = sqrtf(scale[h]) * (part == 0 ? 1.44269504f : 1.0f);
    #pragma unroll
    for (int i = 0; i < 4; i++)
      #pragma unroll
      for (int r = 0; r < 4; r++) {
        int m = m0 + wm + i * 16 + rb + r;
        int nidx = m / SDIM, sp = m - nidx * SDIM;
        int b = nidx >> 3;
        float2 pp = *(const float2*)&pos[((size_t)b * SDIM + sp) * 2];
        float th = (lr < 8 ? pp.x : pp.y) * fr;
        float sth, cth;
        __sincosf(th, &sth, &cth);
        float v0 = acc[i][0][r];
        float v1 = acc[i][1][r];
        float v2 = acc[i][2][r];
        float v3 = acc[i][3][r];
        float ss = v0 * v0 + v1 * v1 + v2 * v2 + v3 * v3;
        ss += __shfl_xor(ss, 1); ss += __shfl_xor(ss, 2);
        ss += __shfl_xor(ss, 4); ss += __shfl_xor(ss, 8);
        float rs = sq * rsqrtf(ss + 1e-6f);
        v0 *= rs; v1 *= rs; v2 *= rs; v3 *= rs;
        float o0 = v0 * cth - v1 * sth;
        float o1 = v1 * cth + v0 * sth;
        u16* trow = T + (size_t)(wm + i * 16 + rb + r) * 136 + wn + lr;
        trow[0]  = f2bf(o0); trow[16] = f2bf(o1);
        trow[32] = f2bf(v2); trow[48] = f2bf(v3);
      }
    __syncthreads();
    u16* dst = (part == 0) ? q : k;
    #pragma unroll
    for (int c = 0; c < 8; c++) {
      int chunk = c * 256 + tid;           // 2048 chunks of u16x8
      int ml = chunk >> 4, sub = chunk & 15;
      int m = m0 + ml;
      int nidx = m / SDIM, sp = m - nidx * SDIM;
      int hl = sub >> 3, e0 = (sub & 7) * 8;
      u16x8 v = *(const u16x8*)&T[(size_t)ml * 136 + sub * 8];
      *(u16x8*)(dst + ((size_t)(nidx * NHEAD + hbase + hl) * SDIM + sp) * EDIM + e0) = v;
    }
  } else {
    #pragma unroll
    for (int i = 0; i < 4; i++)
      #pragma unroll
      for (int j = 0; j < 4; j++)
        #pragma unroll
        for (int r = 0; r < 4; r++)
          T[(size_t)(wn + j * 16 + lr) * 136 + (wm + i * 16 + rb + r)] = f2bf(acc[i][j][r]);
    __syncthreads();
    #pragma unroll
    for (int c = 0; c < 8; c++) {
      int chunk = c * 256 + tid;
      int nl = chunk >> 4, sub = chunk & 15;
      int hl = nl >> 6, e = nl & 63;
      int m = m0 + sub * 8;                // 576%8==0: no nidx straddle in a chunk
      int nidx = m / SDIM, hw = m - nidx * SDIM;
      u16x8 v = *(const u16x8*)&T[(size_t)nl * 136 + sub * 8];
      *(u16x8*)(vt + ((size_t)(nidx * NHEAD + hbase + hl) * EDIM + e) * SDIM + hw) = v;
    }
  }
}

// ---------------- MFMA flash attention v5: 4-wave blocks, K/V staged in LDS ----------
// Block = 4 waves x 48 q-rows = 192 rows. Per 64-col KV-tile: K-tile (64x64) and
// V^T-tile (64x64) staged ONCE via global_load_lds (4 DMA/wave, XOR-swizzled
// source, linear dest), counted vmcnt(4) leaves next tile in flight across the
// barrier. 4x less L2 traffic than per-wave loads; load latency off the chain.
// Fragment reads: chunk ^ (row&7) -> quarter-wave uniform -> conflict-free.
__global__ __launch_bounds__(256, 2) void attn_mfma(const u16* __restrict__ q,
                                                    const u16* __restrict__ k,
                                                    const u16* __restrict__ vt,
                                                    u16* __restrict__ o) {
  __shared__ u16 kbuf[2][4096];            // [buf][64 s][64 e]
  __shared__ u16 vbuf[2][4096];            // [buf][64 e][64 s]
  __shared__ u16 p_lds[4][48][72];
  int L = blockIdx.x;
  int cid = (L & 7) * 72 + (L >> 3);       // 576 = 8 XCD x 72, bijective
  int nh_ = cid / 3;
  int qt = cid - nh_ * 3;
  int n = nh_ / NHEAD, h = nh_ - n * NHEAD;
  int tid = threadIdx.x;
  int wid = tid >> 6, lane = tid & 63;
  int lr = lane & 15, lg = lane >> 4;
  int qbase = qt * 192 + wid * 48;

  const u16* qp = q + ((size_t)nh_ * SDIM + qbase) * EDIM;
  bf16x8 qa[3][2];
  #pragma unroll
  for (int f = 0; f < 3; f++) {
    qa[f][0] = *(const bf16x8*)(qp + (size_t)(f * 16 + lr) * EDIM + lg * 8);
    qa[f][1] = *(const bf16x8*)(qp + (size_t)(f * 16 + lr) * EDIM + 32 + lg * 8);
  }
  const u16* kb = k + (size_t)nh_ * SDIM * EDIM;
  const u16* vb = vt + (size_t)nh_ * EDIM * SDIM;

  // staging geometry: row = wid*16 + is*8 + (lane>>3); row&7 == lane>>3.
  int srow = wid * 16 + (lane >> 3);
  int schunk = (lane & 7) ^ (lane >> 3);   // inverse-swizzled source chunk
  // LDS dest: wave-uniform base + lane*16 (linear, HW requirement)
  auto STAGE = [&](int buf, int s0) {
    #pragma unroll
    for (int is = 0; is < 2; is++) {
      int row = srow + is * 8;
      __builtin_amdgcn_global_load_lds(
          (const __attribute__((address_space(1))) unsigned int*)(kb + (size_t)(s0 + row) * EDIM + schunk * 8),
          (__attribute__((address_space(3))) unsigned int*)(&kbuf[buf][(size_t)(wid * 16 + is * 8 + (lane >> 3)) * 64 + (lane & 7) * 8]),
          16, 0, 0);
      __builtin_amdgcn_global_load_lds(
          (const __attribute__((address_space(1))) unsigned int*)(vb + (size_t)row * SDIM + s0 + schunk * 8),
          (__attribute__((address_space(3))) unsigned int*)(&vbuf[buf][(size_t)(wid * 16 + is * 8 + (lane >> 3)) * 64 + (lane & 7) * 8]),
          16, 0, 0);
    }
  };

  float psum[3] = {0.0f, 0.0f, 0.0f};
  f32x4 oacc[3][4] = {};

  STAGE(0, 0);
  int cur = 0;
  #pragma unroll 1
  for (int kt = 0; kt < 9; kt++) {
    if (kt < 8) {
      STAGE(cur ^ 1, (kt + 1) * 64);
      asm volatile("s_waitcnt vmcnt(4)" ::: "memory");
    } else {
      asm volatile("s_waitcnt vmcnt(0)" ::: "memory");
    }
    __builtin_amdgcn_s_barrier();          // tile kt visible in buf[cur]
    __builtin_amdgcn_sched_barrier(0);
    const u16* kl = kbuf[cur];
    const u16* vl = vbuf[cur];
    // ---- K fragments from LDS (conflict-free swizzled reads) ----
    bf16x8 kf[4][2];
    #pragma unroll
    for (int j = 0; j < 4; j++) {
      kf[j][0] = *(const bf16x8*)&kl[(j * 16 + lr) * 64 + ((lg       ^ (lr & 7)) * 8)];
      kf[j][1] = *(const bf16x8*)&kl[(j * 16 + lr) * 64 + (((lg + 4) ^ (lr & 7)) * 8)];
    }
    // ---- V fragments ----
    bf16x8 vf[2][4];
    #pragma unroll
    for (int ks = 0; ks < 2; ks++)
      #pragma unroll
      for (int et = 0; et < 4; et++)
        vf[ks][et] = *(const bf16x8*)&vl[(et * 16 + lr) * 64 + (((ks * 4 + lg) ^ (lr & 7)) * 8)];
    // ---- swapped QK^T + exp2 softmax (no max: |logit| <= 10·log2e) ----
    #pragma unroll
    for (int f = 0; f < 3; f++) {
      f32x4 sfr[4] = {};
      #pragma unroll
      for (int j = 0; j < 4; j++) {
        sfr[j] = __builtin_amdgcn_mfma_f32_16x16x32_bf16(kf[j][0], qa[f][0], sfr[j], 0, 0, 0);
        sfr[j] = __builtin_amdgcn_mfma_f32_16x16x32_bf16(kf[j][1], qa[f][1], sfr[j], 0, 0, 0);
      }
      float fs = 0.0f;
      #pragma unroll
      for (int j = 0; j < 4; j++) {
        float p0 = exp2f(sfr[j][0]);
        float p1 = exp2f(sfr[j][1]);
        float p2 = exp2f(sfr[j][2]);
        float p3 = exp2f(sfr[j][3]);
        unsigned w0 = cvt_pk_bf16(p0, p1);
        unsigned w1 = cvt_pk_bf16(p2, p3);
        *(unsigned*)&p_lds[wid][f * 16 + lr][j * 16 + lg * 4]     = w0;
        *(unsigned*)&p_lds[wid][f * 16 + lr][j * 16 + lg * 4 + 2] = w1;
        fs += (p0 + p1) + (p2 + p3);
      }
      psum[f] += fs;
    }
    // ---- PV ----
    #pragma unroll
    for (int f = 0; f < 3; f++)
      #pragma unroll
      for (int ks = 0; ks < 2; ks++) {
        bf16x8 pa = *(const bf16x8*)&p_lds[wid][f * 16 + lr][ks * 32 + lg * 8];
        #pragma unroll
        for (int et = 0; et < 4; et++)
          oacc[f][et] = __builtin_amdgcn_mfma_f32_16x16x32_bf16(pa, vf[ks][et], oacc[f][et], 0, 0, 0);
      }
    __builtin_amdgcn_sched_barrier(0);
    __builtin_amdgcn_s_barrier();          // all reads of buf[cur] done
    __builtin_amdgcn_sched_barrier(0);
    cur ^= 1;
  }
  // ---- epilogue ----
  u16* ob = o + ((size_t)n * SDIM + qbase) * CDIM + h * EDIM;
  #pragma unroll
  for (int f = 0; f < 3; f++) {
    float s = psum[f];
    s += __shfl_xor(s, 16);
    s += __shfl_xor(s, 32);
    float inv = 1.0f / s;
    #pragma unroll
    for (int r = 0; r < 4; r++) {
      float invr = __shfl(inv, lg * 4 + r);
      #pragma unroll
      for (int et = 0; et < 4; et++)
        ob[(size_t)(f * 16 + lg * 4 + r) * CDIM + et * 16 + lr] = f2bf(oacc[f][et][r] * invr);
    }
  }
}

// ---------------- out projection + skip, COALESCED via LDS transpose ----------------
__global__ __launch_bounds__(256) void gemm_proj(const u16* __restrict__ o,
                                                 const u16* __restrict__ wo,
                                                 const float* __restrict__ x,
                                                 float* __restrict__ out) {
  __shared__ __align__(16) char smem[128 * 132 * 4];   // 67.6 KB >= 64 KB staging
  u16* ldsA = (u16*)smem;
  u16* ldsB = (u16*)smem + 16384;
  f32x4 acc[4][4] = {};
  int tid = threadIdx.x;
  int m0, n0;
  swz_tile(blockIdx.x, m0, n0);
  gemm_bt_lds(o, wo, CDIM, m0, n0, tid, ldsA, ldsB, acc);
  int lane = tid & 63, wid = tid >> 6;
  int wm = (wid >> 1) * 64, wn = (wid & 1) * 64;
  int lr = lane & 15, rb = (lane >> 4) * 4;
  float* T = (float*)smem;                 // [128 jj][132 m]
  #pragma unroll
  for (int i = 0; i < 4; i++)
    #pragma unroll
    for (int j = 0; j < 4; j++)
      #pragma unroll
      for (int r = 0; r < 4; r++)
        T[(size_t)(wn + j * 16 + lr) * 132 + (wm + i * 16 + rb + r)] = acc[i][j][r];
  __syncthreads();
  #pragma unroll
  for (int c = 0; c < 16; c++) {
    int chunk = c * 256 + tid;             // 4096 chunks of float4
    int nl = chunk >> 5, sub = chunk & 31;
    int m = m0 + sub * 4;                  // 576%4==0: no straddle
    int nidx = m / SDIM, hw = m - nidx * SDIM;
    int b = nidx >> 3, t = nidx & 7;
    int jj = n0 + nl;
    size_t oi = ((size_t)(b * CDIM + jj) * TDIM + t) * SDIM + hw;
    float4 xv = *(const float4*)&x[oi];
    float4 tv = *(const float4*)&T[(size_t)nl * 132 + sub * 4];
    float4 ov;
    ov.x = tv.x + xv.x; ov.y = tv.y + xv.y;
    ov.z = tv.z + xv.z; ov.w = tv.w + xv.w;
    *(float4*)&out[oi] = ov;
  }
}

extern "C" void kernel_launch(void* const* d_in, const int* in_sizes, int n_in,
                              void* d_out, int out_size, void* d_ws, size_t ws_size,
                              hipStream_t stream) {
  const float* x      = (const float*)d_in[0];
  const float* pos    = (const float*)d_in[1];
  const float* cond   = (const float*)d_in[2];
  const float* norm_w = (const float*)d_in[3];
  const float* qkv_w  = (const float*)d_in[4];
  const float* scale  = (const float*)d_in[5];
  const float* out_w  = (const float*)d_in[6];
  const float* freqs  = (const float*)d_in[7];
  float* out = (float*)d_out;

  char* ws = (char*)d_ws;
  size_t off = 0;
  auto alloc = [&](size_t bytes) -> char* {
    char* p = ws + off;
    off = (off + bytes + 255) & ~(size_t)255;
    return p;
  };
  float* cs  = (float*)alloc(2 * CDIM * sizeof(float));
  u16* wq    = (u16*)alloc((size_t)QKVN * CDIM * 2);
  u16* wo    = (u16*)alloc((size_t)CDIM * CDIM * 2);
  u16* xn    = (u16*)alloc((size_t)MDIM * CDIM * 2);
  u16* qb    = (u16*)alloc((size_t)MDIM * CDIM * 2);
  u16* kb    = (u16*)alloc((size_t)MDIM * CDIM * 2);
  u16* vt    = (u16*)alloc((size_t)MDIM * CDIM * 2);
  u16* ob    = (u16*)alloc((size_t)MDIM * CDIM * 2);

  convert_kernel<<<dim3((QKVN * CDIM / 4 + 255) / 256), dim3(256), 0, stream>>>(qkv_w, wq, QKVN * CDIM / 4);
  convert_kernel<<<dim3((CDIM * CDIM / 4 + 255) / 256), dim3(256), 0, stream>>>(out_w, wo, CDIM * CDIM / 4);
  cs_kernel<<<dim3(6), dim3(256), 0, stream>>>(cond, norm_w, cs);
  norm_kernel<<<dim3(SDIM / 16, NROW), dim3(16, 16), 0, stream>>>(x, cs, xn);
  gemm_qkv<<<dim3(8 * 9 * (QKVN / 128)), dim3(256), 0, stream>>>(xn, wq, pos, freqs, scale, qb, kb, vt);
  attn_mfma<<<dim3(576), dim3(256), 0, stream>>>(qb, kb, vt, ob);
  gemm_proj<<<dim3(8 * 9 * (CDIM / 128)), dim3(256), 0, stream>>>(ob, wo, x, out);
}

// Round 14
// 166.685 us; speedup vs baseline: 1.0023x; 1.0023x over previous
//
#include <hip/hip_runtime.h>
#include <hip/hip_bf16.h>

// ---- geometry (fixed by the problem) ----
#define CDIM 768
#define NHEAD 12
#define EDIM 64
#define TDIM 8
#define SDIM 576
#define NROW 16          // B*T
#define MDIM 9216        // NROW*SDIM
#define QKVN 2304

typedef __attribute__((ext_vector_type(4))) float f32x4;
typedef __bf16 bf16x8 __attribute__((ext_vector_type(8)));
typedef unsigned short u16;
typedef __attribute__((ext_vector_type(8))) unsigned short u16x8;

__device__ inline float bf2f(u16 u) {
  union { unsigned int i; float f; } x; x.i = ((unsigned int)u) << 16; return x.f;
}
__device__ inline u16 f2bf(float f) {
  union { float f; unsigned int i; } x; x.f = f;
  unsigned int i = x.i;
  return (u16)((i + 0x7FFFu + ((i >> 16) & 1u)) >> 16);
}
__device__ inline unsigned cvt_pk_bf16(float lo, float hi) {
  unsigned r;
  asm("v_cvt_pk_bf16_f32 %0, %1, %2" : "=v"(r) : "v"(lo), "v"(hi));
  return r;
}

// ---------------- cs = cond @ norm_w^T + 1  (2 x 768) ----------------
__global__ __launch_bounds__(256) void cs_kernel(const float* __restrict__ cond,
                                                 const float* __restrict__ nw,
                                                 float* __restrict__ cs) {
  int idx = blockIdx.x * 256 + threadIdx.x;      // 0..1535
  int b = idx / CDIM, c = idx % CDIM;
  const float* cr = cond + (size_t)b * CDIM;
  const float* wr = nw + (size_t)c * CDIM;
  float s = 1.0f;
  for (int j = 0; j < CDIM; j += 4) {
    float4 a = *(const float4*)(cr + j);
    float4 w = *(const float4*)(wr + j);
    s = fmaf(a.x, w.x, s); s = fmaf(a.y, w.y, s);
    s = fmaf(a.z, w.z, s); s = fmaf(a.w, w.w, s);
  }
  cs[idx] = s;
}

// ---------------- RMS-norm * cs -> xn (M, C) bf16, one-pass via LDS ----------------
__global__ __launch_bounds__(256) void norm_kernel(const float* __restrict__ x,
                                                   const float* __restrict__ cs,
                                                   u16* __restrict__ xn) {
  __shared__ float xs[16][772];
  __shared__ float red[16][17];
  __shared__ float rfac[16];
  int n = blockIdx.y;
  int hw0 = blockIdx.x * 16;
  int b = n >> 3, t = n & 7;
  int tx = threadIdx.x, ty = threadIdx.y;
  const float* xb = x + ((size_t)b * CDIM * TDIM + t) * SDIM;
  float acc = 0.0f;
  for (int c = ty; c < CDIM; c += 16) {
    float v = xb[(size_t)c * (TDIM * SDIM) + hw0 + tx];
    xs[tx][c] = v;
    acc = fmaf(v, v, acc);
  }
  red[ty][tx] = acc;
  __syncthreads();
  if (ty == 0) {
    float s = 0.0f;
    #pragma unroll
    for (int j = 0; j < 16; j++) s += red[j][tx];
    rfac[tx] = rsqrtf(s * (1.0f / (float)CDIM) + 1e-6f);
  }
  __syncthreads();
  const float* csb = cs + (size_t)b * CDIM;
  int flat = ty * 16 + tx;
  #pragma unroll
  for (int i = 0; i < 6; i++) {
    int idx = i * 256 + flat;
    int row = idx / 96;
    int cseg = idx - row * 96;
    int c0 = cseg * 8;
    float rf = rfac[row];
    float4 a0 = *(const float4*)&xs[row][c0];
    float4 a1 = *(const float4*)&xs[row][c0 + 4];
    float4 w0 = *(const float4*)(csb + c0);
    float4 w1 = *(const float4*)(csb + c0 + 4);
    u16x8 ov;
    ov[0] = f2bf(a0.x * w0.x * rf); ov[1] = f2bf(a0.y * w0.y * rf);
    ov[2] = f2bf(a0.z * w0.z * rf); ov[3] = f2bf(a0.w * w0.w * rf);
    ov[4] = f2bf(a1.x * w1.x * rf); ov[5] = f2bf(a1.y * w1.y * rf);
    ov[6] = f2bf(a1.z * w1.z * rf); ov[7] = f2bf(a1.w * w1.w * rf);
    *(u16x8*)(xn + ((size_t)n * SDIM + hw0 + row) * CDIM + c0) = ov;
  }
}

// ---------------- f32 -> bf16 weight convert ----------------
__global__ __launch_bounds__(256) void convert_kernel(const float* __restrict__ src,
                                                      u16* __restrict__ dst, int count4) {
  int i = blockIdx.x * 256 + threadIdx.x;
  if (i < count4) {
    float4 v = *(const float4*)(src + (size_t)i * 4);
    u16* d = dst + (size_t)i * 4;
    d[0] = f2bf(v.x); d[1] = f2bf(v.y); d[2] = f2bf(v.z); d[3] = f2bf(v.w);
  }
}

// ---------------- MFMA GEMM core: dbuf + counted vmcnt ----------------
__device__ __forceinline__ void gemm_bt_lds(const u16* __restrict__ A,
                                            const u16* __restrict__ B,
                                            int K, int m0, int n0, int tid,
                                            u16* ldsA, u16* ldsB,
                                            f32x4 acc[4][4]) {
  int lane = tid & 63;
  int wid = tid >> 6;
  int wm = (wid >> 1) * 64, wn = (wid & 1) * 64;
  int lr = lane & 15, lg = lane >> 4;
  const u16* gA = A + (size_t)(m0 + wid * 32 + (lane >> 3)) * K + (((lane & 7) ^ (lane >> 3)) * 8);
  const u16* gB = B + (size_t)(n0 + wid * 32 + (lane >> 3)) * K + (((lane & 7) ^ (lane >> 3)) * 8);
  u16* dA = ldsA + wid * 2048;
  u16* dB = ldsB + wid * 2048;
  auto STAGE = [&](int buf, int k0) {
    u16* dAb = dA + buf * 8192;
    u16* dBb = dB + buf * 8192;
    #pragma unroll
    for (int is = 0; is < 4; is++) {
      __builtin_amdgcn_global_load_lds(
          (const __attribute__((address_space(1))) unsigned int*)(gA + (size_t)(is * 8) * K + k0),
          (__attribute__((address_space(3))) unsigned int*)(dAb + is * 512),
          16, 0, 0);
      __builtin_amdgcn_global_load_lds(
          (const __attribute__((address_space(1))) unsigned int*)(gB + (size_t)(is * 8) * K + k0),
          (__attribute__((address_space(3))) unsigned int*)(dBb + is * 512),
          16, 0, 0);
    }
  };
  int nt = K >> 6;
  STAGE(0, 0);
  int cur = 0;
  #pragma unroll 1
  for (int t = 0; t < nt; t++) {
    if (t + 1 < nt) {
      STAGE(cur ^ 1, (t + 1) * 64);
      asm volatile("s_waitcnt vmcnt(8)" ::: "memory");
    } else {
      asm volatile("s_waitcnt vmcnt(0)" ::: "memory");
    }
    __builtin_amdgcn_s_barrier();
    __builtin_amdgcn_sched_barrier(0);
    const u16* lA = ldsA + cur * 8192;
    const u16* lB = ldsB + cur * 8192;
    #pragma unroll
    for (int kk = 0; kk < 2; kk++) {
      bf16x8 af[4], bfr[4];
      #pragma unroll
      for (int i = 0; i < 4; i++)
        af[i]  = *(const bf16x8*)&lA[(wm + i * 16 + lr) * 64 + (((lg + 4 * kk) ^ (lr & 7)) * 8)];
      #pragma unroll
      for (int j = 0; j < 4; j++)
        bfr[j] = *(const bf16x8*)&lB[(wn + j * 16 + lr) * 64 + (((lg + 4 * kk) ^ (lr & 7)) * 8)];
      #pragma unroll
      for (int i = 0; i < 4; i++)
        #pragma unroll
        for (int j = 0; j < 4; j++)
          acc[i][j] = __builtin_amdgcn_mfma_f32_16x16x32_bf16(af[i], bfr[j], acc[i][j], 0, 0, 0);
    }
    __builtin_amdgcn_sched_barrier(0);
    __builtin_amdgcn_s_barrier();
    __builtin_amdgcn_sched_barrier(0);
    cur ^= 1;
  }
}

// XCD-chunk swizzle: grid = 8 XCD * 9 m-blocks * NBLK n-blocks (bijective).
__device__ __forceinline__ void swz_tile(int L, int& m0, int& n0) {
  int xcd = L & 7, loc = L >> 3;
  int nblk = loc / 9, mloc = loc - nblk * 9;
  m0 = (xcd * 9 + mloc) * 128;
  n0 = nblk * 128;
}

// ---------------- QKV GEMM: fused cos-norm+RoPE, COALESCED LDS-staged stores ----------
__global__ __launch_bounds__(256) void gemm_qkv(const u16* __restrict__ xn,
                                                const u16* __restrict__ wq,
                                                const float* __restrict__ pos,
                                                const float* __restrict__ freqs,
                                                const float* __restrict__ scale,
                                                u16* __restrict__ q,
                                                u16* __restrict__ k,
                                                u16* __restrict__ vt) {
  __shared__ u16 smem[32768];              // 64 KB: staging dbuf; reused by epilogue
  u16* ldsA = smem;
  u16* ldsB = smem + 16384;
  f32x4 acc[4][4] = {};
  int tid = threadIdx.x;
  int m0, n0;
  swz_tile(blockIdx.x, m0, n0);
  gemm_bt_lds(xn, wq, CDIM, m0, n0, tid, ldsA, ldsB, acc);
  int lane = tid & 63, wid = tid >> 6;
  int wm = (wid >> 1) * 64, wn = (wid & 1) * 64;
  int lr = lane & 15, rb = (lane >> 4) * 4;
  int part = n0 / CDIM;                    // block-uniform
  int hbase = (n0 - part * CDIM) >> 6;     // block-uniform head base (2 heads/block)
  u16* T = smem;                           // [128][136]
  if (part < 2) {
    int h = hbase + (wn >> 6);             // wave-uniform head
    float fr = freqs[h * 8 + (lr & 7)];
    float sq = sqrtf(scale[h]) * (part == 0 ? 1.44269504f : 1.0f);
    #pragma unroll
    for (int i = 0; i < 4; i++)
      #pragma unroll
      for (int r = 0; r < 4; r++) {
        int m = m0 + wm + i * 16 + rb + r;
        int nidx = m / SDIM, sp = m - nidx * SDIM;
        int b = nidx >> 3;
        float2 pp = *(const float2*)&pos[((size_t)b * SDIM + sp) * 2];
        float th = (lr < 8 ? pp.x : pp.y) * fr;
        float sth, cth;
        __sincosf(th, &sth, &cth);
        float v0 = acc[i][0][r];
        float v1 = acc[i][1][r];
        float v2 = acc[i][2][r];
        float v3 = acc[i][3][r];
        float ss = v0 * v0 + v1 * v1 + v2 * v2 + v3 * v3;
        ss += __shfl_xor(ss, 1); ss += __shfl_xor(ss, 2);
        ss += __shfl_xor(ss, 4); ss += __shfl_xor(ss, 8);
        float rs = sq * rsqrtf(ss + 1e-6f);
        v0 *= rs; v1 *= rs; v2 *= rs; v3 *= rs;
        float o0 = v0 * cth - v1 * sth;
        float o1 = v1 * cth + v0 * sth;
        u16* trow = T + (size_t)(wm + i * 16 + rb + r) * 136 + wn + lr;
        trow[0]  = f2bf(o0); trow[16] = f2bf(o1);
        trow[32] = f2bf(v2); trow[48] = f2bf(v3);
      }
    __syncthreads();
    u16* dst = (part == 0) ? q : k;
    #pragma unroll
    for (int c = 0; c < 8; c++) {
      int chunk = c * 256 + tid;           // 2048 chunks of u16x8
      int ml = chunk >> 4, sub = chunk & 15;
      int m = m0 + ml;
      int nidx = m / SDIM, sp = m - nidx * SDIM;
      int hl = sub >> 3, e0 = (sub & 7) * 8;
      u16x8 v = *(const u16x8*)&T[(size_t)ml * 136 + sub * 8];
      *(u16x8*)(dst + ((size_t)(nidx * NHEAD + hbase + hl) * SDIM + sp) * EDIM + e0) = v;
    }
  } else {
    #pragma unroll
    for (int i = 0; i < 4; i++)
      #pragma unroll
      for (int j = 0; j < 4; j++)
        #pragma unroll
        for (int r = 0; r < 4; r++)
          T[(size_t)(wn + j * 16 + lr) * 136 + (wm + i * 16 + rb + r)] = f2bf(acc[i][j][r]);
    __syncthreads();
    #pragma unroll
    for (int c = 0; c < 8; c++) {
      int chunk = c * 256 + tid;
      int nl = chunk >> 4, sub = chunk & 15;
      int hl = nl >> 6, e = nl & 63;
      int m = m0 + sub * 8;                // 576%8==0: no nidx straddle in a chunk
      int nidx = m / SDIM, hw = m - nidx * SDIM;
      u16x8 v = *(const u16x8*)&T[(size_t)nl * 136 + sub * 8];
      *(u16x8*)(vt + ((size_t)(nidx * NHEAD + hbase + hl) * EDIM + e) * SDIM + hw) = v;
    }
  }
}

// ---------------- MFMA flash attention v5: 4-wave blocks, K/V staged in LDS ----------
// Block = 4 waves x 48 q-rows = 192 rows. Per 64-col KV-tile: K-tile (64x64) and
// V^T-tile (64x64) staged ONCE via global_load_lds (4 DMA/wave, XOR-swizzled
// source, linear dest), counted vmcnt(4) leaves next tile in flight across the
// barrier. 4x less L2 traffic than per-wave loads; load latency off the chain.
// Fragment reads: chunk ^ (row&7) -> quarter-wave uniform -> conflict-free.
__global__ __launch_bounds__(256, 2) void attn_mfma(const u16* __restrict__ q,
                                                    const u16* __restrict__ k,
                                                    const u16* __restrict__ vt,
                                                    u16* __restrict__ o) {
  __shared__ u16 kbuf[2][4096];            // [buf][64 s][64 e]
  __shared__ u16 vbuf[2][4096];            // [buf][64 e][64 s]
  __shared__ u16 p_lds[4][48][72];
  int L = blockIdx.x;
  int cid = (L & 7) * 72 + (L >> 3);       // 576 = 8 XCD x 72, bijective
  int nh_ = cid / 3;
  int qt = cid - nh_ * 3;
  int n = nh_ / NHEAD, h = nh_ - n * NHEAD;
  int tid = threadIdx.x;
  int wid = tid >> 6, lane = tid & 63;
  int lr = lane & 15, lg = lane >> 4;
  int qbase = qt * 192 + wid * 48;

  const u16* qp = q + ((size_t)nh_ * SDIM + qbase) * EDIM;
  bf16x8 qa[3][2];
  #pragma unroll
  for (int f = 0; f < 3; f++) {
    qa[f][0] = *(const bf16x8*)(qp + (size_t)(f * 16 + lr) * EDIM + lg * 8);
    qa[f][1] = *(const bf16x8*)(qp + (size_t)(f * 16 + lr) * EDIM + 32 + lg * 8);
  }
  const u16* kb = k + (size_t)nh_ * SDIM * EDIM;
  const u16* vb = vt + (size_t)nh_ * EDIM * SDIM;

  // staging geometry: row = wid*16 + is*8 + (lane>>3); row&7 == lane>>3.
  int srow = wid * 16 + (lane >> 3);
  int schunk = (lane & 7) ^ (lane >> 3);   // inverse-swizzled source chunk
  // LDS dest: wave-uniform base + lane*16 (linear, HW requirement)
  auto STAGE = [&](int buf, int s0) {
    #pragma unroll
    for (int is = 0; is < 2; is++) {
      int row = srow + is * 8;
      __builtin_amdgcn_global_load_lds(
          (const __attribute__((address_space(1))) unsigned int*)(kb + (size_t)(s0 + row) * EDIM + schunk * 8),
          (__attribute__((address_space(3))) unsigned int*)(&kbuf[buf][(size_t)(wid * 16 + is * 8 + (lane >> 3)) * 64 + (lane & 7) * 8]),
          16, 0, 0);
      __builtin_amdgcn_global_load_lds(
          (const __attribute__((address_space(1))) unsigned int*)(vb + (size_t)row * SDIM + s0 + schunk * 8),
          (__attribute__((address_space(3))) unsigned int*)(&vbuf[buf][(size_t)(wid * 16 + is * 8 + (lane >> 3)) * 64 + (lane & 7) * 8]),
          16, 0, 0);
    }
  };

  float psum[3] = {0.0f, 0.0f, 0.0f};
  f32x4 oacc[3][4] = {};

  STAGE(0, 0);
  int cur = 0;
  #pragma unroll 1
  for (int kt = 0; kt < 9; kt++) {
    if (kt < 8) {
      STAGE(cur ^ 1, (kt + 1) * 64);
      asm volatile("s_waitcnt vmcnt(4)" ::: "memory");
    } else {
      asm volatile("s_waitcnt vmcnt(0)" ::: "memory");
    }
    __builtin_amdgcn_s_barrier();          // tile kt visible in buf[cur]
    __builtin_amdgcn_sched_barrier(0);
    const u16* kl = kbuf[cur];
    const u16* vl = vbuf[cur];
    // ---- K fragments from LDS (conflict-free swizzled reads) ----
    bf16x8 kf[4][2];
    #pragma unroll
    for (int j = 0; j < 4; j++) {
      kf[j][0] = *(const bf16x8*)&kl[(j * 16 + lr) * 64 + ((lg       ^ (lr & 7)) * 8)];
      kf[j][1] = *(const bf16x8*)&kl[(j * 16 + lr) * 64 + (((lg + 4) ^ (lr & 7)) * 8)];
    }
    // ---- V fragments ----
    bf16x8 vf[2][4];
    #pragma unroll
    for (int ks = 0; ks < 2; ks++)
      #pragma unroll
      for (int et = 0; et < 4; et++)
        vf[ks][et] = *(const bf16x8*)&vl[(et * 16 + lr) * 64 + (((ks * 4 + lg) ^ (lr & 7)) * 8)];
    // ---- swapped QK^T + exp2 softmax (no max: |logit| <= 10·log2e) ----
    #pragma unroll
    for (int f = 0; f < 3; f++) {
      f32x4 sfr[4] = {};
      #pragma unroll
      for (int j = 0; j < 4; j++) {
        sfr[j] = __builtin_amdgcn_mfma_f32_16x16x32_bf16(kf[j][0], qa[f][0], sfr[j], 0, 0, 0);
        sfr[j] = __builtin_amdgcn_mfma_f32_16x16x32_bf16(kf[j][1], qa[f][1], sfr[j], 0, 0, 0);
      }
      float fs = 0.0f;
      #pragma unroll
      for (int j = 0; j < 4; j++) {
        float p0 = exp2f(sfr[j][0]);
        float p1 = exp2f(sfr[j][1]);
        float p2 = exp2f(sfr[j][2]);
        float p3 = exp2f(sfr[j][3]);
        unsigned w0 = cvt_pk_bf16(p0, p1);
        unsigned w1 = cvt_pk_bf16(p2, p3);
        *(unsigned*)&p_lds[wid][f * 16 + lr][j * 16 + lg * 4]     = w0;
        *(unsigned*)&p_lds[wid][f * 16 + lr][j * 16 + lg * 4 + 2] = w1;
        fs += (p0 + p1) + (p2 + p3);
      }
      psum[f] += fs;
    }
    // ---- PV ----
    #pragma unroll
    for (int f = 0; f < 3; f++)
      #pragma unroll
      for (int ks = 0; ks < 2; ks++) {
        bf16x8 pa = *(const bf16x8*)&p_lds[wid][f * 16 + lr][ks * 32 + lg * 8];
        #pragma unroll
        for (int et = 0; et < 4; et++)
          oacc[f][et] = __builtin_amdgcn_mfma_f32_16x16x32_bf16(pa, vf[ks][et], oacc[f][et], 0, 0, 0);
      }
    __builtin_amdgcn_sched_barrier(0);
    __builtin_amdgcn_s_barrier();          // all reads of buf[cur] done
    __builtin_amdgcn_sched_barrier(0);
    cur ^= 1;
  }
  // ---- epilogue ----
  u16* ob = o + ((size_t)n * SDIM + qbase) * CDIM + h * EDIM;
  #pragma unroll
  for (int f = 0; f < 3; f++) {
    float s = psum[f];
    s += __shfl_xor(s, 16);
    s += __shfl_xor(s, 32);
    float inv = 1.0f / s;
    #pragma unroll
    for (int r = 0; r < 4; r++) {
      float invr = __shfl(inv, lg * 4 + r);
      #pragma unroll
      for (int et = 0; et < 4; et++)
        ob[(size_t)(f * 16 + lg * 4 + r) * CDIM + et * 16 + lr] = f2bf(oacc[f][et][r] * invr);
    }
  }
}

// ---------------- out projection + skip, COALESCED via LDS transpose ----------------
__global__ __launch_bounds__(256) void gemm_proj(const u16* __restrict__ o,
                                                 const u16* __restrict__ wo,
                                                 const float* __restrict__ x,
                                                 float* __restrict__ out) {
  __shared__ __align__(16) char smem[128 * 132 * 4];   // 67.6 KB >= 64 KB staging
  u16* ldsA = (u16*)smem;
  u16* ldsB = (u16*)smem + 16384;
  f32x4 acc[4][4] = {};
  int tid = threadIdx.x;
  int m0, n0;
  swz_tile(blockIdx.x, m0, n0);
  gemm_bt_lds(o, wo, CDIM, m0, n0, tid, ldsA, ldsB, acc);
  int lane = tid & 63, wid = tid >> 6;
  int wm = (wid >> 1) * 64, wn = (wid & 1) * 64;
  int lr = lane & 15, rb = (lane >> 4) * 4;
  float* T = (float*)smem;                 // [128 jj][132 m]
  #pragma unroll
  for (int i = 0; i < 4; i++)
    #pragma unroll
    for (int j = 0; j < 4; j++)
      #pragma unroll
      for (int r = 0; r < 4; r++)
        T[(size_t)(wn + j * 16 + lr) * 132 + (wm + i * 16 + rb + r)] = acc[i][j][r];
  __syncthreads();
  #pragma unroll
  for (int c = 0; c < 16; c++) {
    int chunk = c * 256 + tid;             // 4096 chunks of float4
    int nl = chunk >> 5, sub = chunk & 31;
    int m = m0 + sub * 4;                  // 576%4==0: no straddle
    int nidx = m / SDIM, hw = m - nidx * SDIM;
    int b = nidx >> 3, t = nidx & 7;
    int jj = n0 + nl;
    size_t oi = ((size_t)(b * CDIM + jj) * TDIM + t) * SDIM + hw;
    float4 xv = *(const float4*)&x[oi];
    float4 tv = *(const float4*)&T[(size_t)nl * 132 + sub * 4];
    float4 ov;
    ov.x = tv.x + xv.x; ov.y = tv.y + xv.y;
    ov.z = tv.z + xv.z; ov.w = tv.w + xv.w;
    *(float4*)&out[oi] = ov;
  }
}

extern "C" void kernel_launch(void* const* d_in, const int* in_sizes, int n_in,
                              void* d_out, int out_size, void* d_ws, size_t ws_size,
                              hipStream_t stream) {
  const float* x      = (const float*)d_in[0];
  const float* pos    = (const float*)d_in[1];
  const float* cond   = (const float*)d_in[2];
  const float* norm_w = (const float*)d_in[3];
  const float* qkv_w  = (const float*)d_in[4];
  const float* scale  = (const float*)d_in[5];
  const float* out_w  = (const float*)d_in[6];
  const float* freqs  = (const float*)d_in[7];
  float* out = (float*)d_out;

  char* ws = (char*)d_ws;
  size_t off = 0;
  auto alloc = [&](size_t bytes) -> char* {
    char* p = ws + off;
    off = (off + bytes + 255) & ~(size_t)255;
    return p;
  };
  float* cs  = (float*)alloc(2 * CDIM * sizeof(float));
  u16* wq    = (u16*)alloc((size_t)QKVN * CDIM * 2);
  u16* wo    = (u16*)alloc((size_t)CDIM * CDIM * 2);
  u16* xn    = (u16*)alloc((size_t)MDIM * CDIM * 2);
  u16* qb    = (u16*)alloc((size_t)MDIM * CDIM * 2);
  u16* kb    = (u16*)alloc((size_t)MDIM * CDIM * 2);
  u16* vt    = (u16*)alloc((size_t)MDIM * CDIM * 2);
  u16* ob    = (u16*)alloc((size_t)MDIM * CDIM * 2);

  convert_kernel<<<dim3((QKVN * CDIM / 4 + 255) / 256), dim3(256), 0, stream>>>(qkv_w, wq, QKVN * CDIM / 4);
  convert_kernel<<<dim3((CDIM * CDIM / 4 + 255) / 256), dim3(256), 0, stream>>>(out_w, wo, CDIM * CDIM / 4);
  cs_kernel<<<dim3(6), dim3(256), 0, stream>>>(cond, norm_w, cs);
  norm_kernel<<<dim3(SDIM / 16, NROW), dim3(16, 16), 0, stream>>>(x, cs, xn);
  gemm_qkv<<<dim3(8 * 9 * (QKVN / 128)), dim3(256), 0, stream>>>(xn, wq, pos, freqs, scale, qb, kb, vt);
  attn_mfma<<<dim3(576), dim3(256), 0, stream>>>(qb, kb, vt, ob);
  gemm_proj<<<dim3(8 * 9 * (CDIM / 128)), dim3(256), 0, stream>>>(ob, wo, x, out);
}

// Round 15
// 163.856 us; speedup vs baseline: 1.0196x; 1.0173x over previous
//
#include <hip/hip_runtime.h>
#include <hip/hip_bf16.h>

// ---- geometry (fixed by the problem) ----
#define CDIM 768
#define NHEAD 12
#define EDIM 64
#define TDIM 8
#define SDIM 576
#define NROW 16          // B*T
#define MDIM 9216        // NROW*SDIM
#define QKVN 2304

typedef __attribute__((ext_vector_type(4))) float f32x4;
typedef __bf16 bf16x8 __attribute__((ext_vector_type(8)));
typedef unsigned short u16;
typedef __attribute__((ext_vector_type(8))) unsigned short u16x8;

__device__ inline float bf2f(u16 u) {
  union { unsigned int i; float f; } x; x.i = ((unsigned int)u) << 16; return x.f;
}
__device__ inline u16 f2bf(float f) {
  union { float f; unsigned int i; } x; x.f = f;
  unsigned int i = x.i;
  return (u16)((i + 0x7FFFu + ((i >> 16) & 1u)) >> 16);
}
__device__ inline unsigned cvt_pk_bf16(float lo, float hi) {
  unsigned r;
  asm("v_cvt_pk_bf16_f32 %0, %1, %2" : "=v"(r) : "v"(lo), "v"(hi));
  return r;
}

// ---------------- prep: weight converts + cs + RoPE trig table, one kernel ----------
// sections (exact multiples of 256):
//   [0,1728)    convert qkv_w -> wq        (442368 float4)
//   [1728,2304) convert out_w -> wo        (147456 float4)
//   [2304,2310) cs = cond @ norm_w^T + 1   (1536)
//   [2310,3174) trig[(bs*12+h)*16+j] = (cos,sin)(pos[bs][j>>3] * freqs[h][j&7])
__global__ __launch_bounds__(256) void prep_kernel(const float* __restrict__ qkv_w,
                                                   u16* __restrict__ wq,
                                                   const float* __restrict__ out_w,
                                                   u16* __restrict__ wo,
                                                   const float* __restrict__ cond,
                                                   const float* __restrict__ nw,
                                                   float* __restrict__ cs,
                                                   const float* __restrict__ pos,
                                                   const float* __restrict__ freqs,
                                                   float2* __restrict__ trig) {
  int bid = blockIdx.x;
  int tid = threadIdx.x;
  if (bid < 1728) {
    int i = bid * 256 + tid;
    float4 v = *(const float4*)(qkv_w + (size_t)i * 4);
    u16* d = wq + (size_t)i * 4;
    d[0] = f2bf(v.x); d[1] = f2bf(v.y); d[2] = f2bf(v.z); d[3] = f2bf(v.w);
  } else if (bid < 2304) {
    int i = (bid - 1728) * 256 + tid;
    float4 v = *(const float4*)(out_w + (size_t)i * 4);
    u16* d = wo + (size_t)i * 4;
    d[0] = f2bf(v.x); d[1] = f2bf(v.y); d[2] = f2bf(v.z); d[3] = f2bf(v.w);
  } else if (bid < 2310) {
    int idx = (bid - 2304) * 256 + tid;          // 0..1535
    int b = idx / CDIM, c = idx - b * CDIM;
    const float* cr = cond + (size_t)b * CDIM;
    const float* wr = nw + (size_t)c * CDIM;
    float s = 1.0f;
    for (int j = 0; j < CDIM; j += 4) {
      float4 a = *(const float4*)(cr + j);
      float4 w = *(const float4*)(wr + j);
      s = fmaf(a.x, w.x, s); s = fmaf(a.y, w.y, s);
      s = fmaf(a.z, w.z, s); s = fmaf(a.w, w.w, s);
    }
    cs[idx] = s;
  } else {
    int idx = (bid - 2310) * 256 + tid;          // 0..221183
    int j = idx & 15;
    int h = (idx >> 4) % NHEAD;
    int bs = idx / (16 * NHEAD);                 // b*576 + sp
    float p = pos[(size_t)bs * 2 + (j >> 3)];
    float th = p * freqs[h * 8 + (j & 7)];
    float sn, cn;
    __sincosf(th, &sn, &cn);
    trig[idx] = make_float2(cn, sn);
  }
}

// ---------------- RMS-norm * cs -> xn (M, C) bf16, one-pass via LDS ----------------
__global__ __launch_bounds__(256) void norm_kernel(const float* __restrict__ x,
                                                   const float* __restrict__ cs,
                                                   u16* __restrict__ xn) {
  __shared__ float xs[16][772];
  __shared__ float red[16][17];
  __shared__ float rfac[16];
  int n = blockIdx.y;
  int hw0 = blockIdx.x * 16;
  int b = n >> 3, t = n & 7;
  int tx = threadIdx.x, ty = threadIdx.y;
  const float* xb = x + ((size_t)b * CDIM * TDIM + t) * SDIM;
  float acc = 0.0f;
  for (int c = ty; c < CDIM; c += 16) {
    float v = xb[(size_t)c * (TDIM * SDIM) + hw0 + tx];
    xs[tx][c] = v;
    acc = fmaf(v, v, acc);
  }
  red[ty][tx] = acc;
  __syncthreads();
  if (ty == 0) {
    float s = 0.0f;
    #pragma unroll
    for (int j = 0; j < 16; j++) s += red[j][tx];
    rfac[tx] = rsqrtf(s * (1.0f / (float)CDIM) + 1e-6f);
  }
  __syncthreads();
  const float* csb = cs + (size_t)b * CDIM;
  int flat = ty * 16 + tx;
  #pragma unroll
  for (int i = 0; i < 6; i++) {
    int idx = i * 256 + flat;
    int row = idx / 96;
    int cseg = idx - row * 96;
    int c0 = cseg * 8;
    float rf = rfac[row];
    float4 a0 = *(const float4*)&xs[row][c0];
    float4 a1 = *(const float4*)&xs[row][c0 + 4];
    float4 w0 = *(const float4*)(csb + c0);
    float4 w1 = *(const float4*)(csb + c0 + 4);
    u16x8 ov;
    ov[0] = f2bf(a0.x * w0.x * rf); ov[1] = f2bf(a0.y * w0.y * rf);
    ov[2] = f2bf(a0.z * w0.z * rf); ov[3] = f2bf(a0.w * w0.w * rf);
    ov[4] = f2bf(a1.x * w1.x * rf); ov[5] = f2bf(a1.y * w1.y * rf);
    ov[6] = f2bf(a1.z * w1.z * rf); ov[7] = f2bf(a1.w * w1.w * rf);
    *(u16x8*)(xn + ((size_t)n * SDIM + hw0 + row) * CDIM + c0) = ov;
  }
}

// ---------------- MFMA GEMM core: dbuf + counted vmcnt ----------------
__device__ __forceinline__ void gemm_bt_lds(const u16* __restrict__ A,
                                            const u16* __restrict__ B,
                                            int K, int m0, int n0, int tid,
                                            u16* ldsA, u16* ldsB,
                                            f32x4 acc[4][4]) {
  int lane = tid & 63;
  int wid = tid >> 6;
  int wm = (wid >> 1) * 64, wn = (wid & 1) * 64;
  int lr = lane & 15, lg = lane >> 4;
  const u16* gA = A + (size_t)(m0 + wid * 32 + (lane >> 3)) * K + (((lane & 7) ^ (lane >> 3)) * 8);
  const u16* gB = B + (size_t)(n0 + wid * 32 + (lane >> 3)) * K + (((lane & 7) ^ (lane >> 3)) * 8);
  u16* dA = ldsA + wid * 2048;
  u16* dB = ldsB + wid * 2048;
  auto STAGE = [&](int buf, int k0) {
    u16* dAb = dA + buf * 8192;
    u16* dBb = dB + buf * 8192;
    #pragma unroll
    for (int is = 0; is < 4; is++) {
      __builtin_amdgcn_global_load_lds(
          (const __attribute__((address_space(1))) unsigned int*)(gA + (size_t)(is * 8) * K + k0),
          (__attribute__((address_space(3))) unsigned int*)(dAb + is * 512),
          16, 0, 0);
      __builtin_amdgcn_global_load_lds(
          (const __attribute__((address_space(1))) unsigned int*)(gB + (size_t)(is * 8) * K + k0),
          (__attribute__((address_space(3))) unsigned int*)(dBb + is * 512),
          16, 0, 0);
    }
  };
  int nt = K >> 6;
  STAGE(0, 0);
  int cur = 0;
  #pragma unroll 1
  for (int t = 0; t < nt; t++) {
    if (t + 1 < nt) {
      STAGE(cur ^ 1, (t + 1) * 64);
      asm volatile("s_waitcnt vmcnt(8)" ::: "memory");
    } else {
      asm volatile("s_waitcnt vmcnt(0)" ::: "memory");
    }
    __builtin_amdgcn_s_barrier();
    __builtin_amdgcn_sched_barrier(0);
    const u16* lA = ldsA + cur * 8192;
    const u16* lB = ldsB + cur * 8192;
    #pragma unroll
    for (int kk = 0; kk < 2; kk++) {
      bf16x8 af[4], bfr[4];
      #pragma unroll
      for (int i = 0; i < 4; i++)
        af[i]  = *(const bf16x8*)&lA[(wm + i * 16 + lr) * 64 + (((lg + 4 * kk) ^ (lr & 7)) * 8)];
      #pragma unroll
      for (int j = 0; j < 4; j++)
        bfr[j] = *(const bf16x8*)&lB[(wn + j * 16 + lr) * 64 + (((lg + 4 * kk) ^ (lr & 7)) * 8)];
      #pragma unroll
      for (int i = 0; i < 4; i++)
        #pragma unroll
        for (int j = 0; j < 4; j++)
          acc[i][j] = __builtin_amdgcn_mfma_f32_16x16x32_bf16(af[i], bfr[j], acc[i][j], 0, 0, 0);
    }
    __builtin_amdgcn_sched_barrier(0);
    __builtin_amdgcn_s_barrier();
    __builtin_amdgcn_sched_barrier(0);
    cur ^= 1;
  }
}

// XCD-chunk swizzle: grid = 8 XCD * 9 m-blocks * NBLK n-blocks (bijective).
__device__ __forceinline__ void swz_tile(int L, int& m0, int& n0) {
  int xcd = L & 7, loc = L >> 3;
  int nblk = loc / 9, mloc = loc - nblk * 9;
  m0 = (xcd * 9 + mloc) * 128;
  n0 = nblk * 128;
}

// ---------------- QKV GEMM: fused cos-norm+RoPE (table), coalesced stores ----------
__global__ __launch_bounds__(256) void gemm_qkv(const u16* __restrict__ xn,
                                                const u16* __restrict__ wq,
                                                const float2* __restrict__ trig,
                                                const float* __restrict__ scale,
                                                u16* __restrict__ q,
                                                u16* __restrict__ k,
                                                u16* __restrict__ vt) {
  __shared__ u16 smem[32768];              // 64 KB: staging dbuf; reused by epilogue
  u16* ldsA = smem;
  u16* ldsB = smem + 16384;
  f32x4 acc[4][4] = {};
  int tid = threadIdx.x;
  int m0, n0;
  swz_tile(blockIdx.x, m0, n0);
  gemm_bt_lds(xn, wq, CDIM, m0, n0, tid, ldsA, ldsB, acc);
  int lane = tid & 63, wid = tid >> 6;
  int wm = (wid >> 1) * 64, wn = (wid & 1) * 64;
  int lr = lane & 15, rb = (lane >> 4) * 4;
  int part = n0 / CDIM;                    // block-uniform
  int hbase = (n0 - part * CDIM) >> 6;     // block-uniform head base (2 heads/block)
  u16* T = smem;                           // [128][136]
  if (part < 2) {
    int h = hbase + (wn >> 6);             // wave-uniform head
    float sq = sqrtf(scale[h]) * (part == 0 ? 1.44269504f : 1.0f);
    #pragma unroll
    for (int i = 0; i < 4; i++)
      #pragma unroll
      for (int r = 0; r < 4; r++) {
        int m = m0 + wm + i * 16 + rb + r;
        int nidx = m / SDIM, sp = m - nidx * SDIM;
        int b = nidx >> 3;
        float2 cssn = trig[(((size_t)b * SDIM + sp) * NHEAD + h) * 16 + lr];
        float v0 = acc[i][0][r];
        float v1 = acc[i][1][r];
        float v2 = acc[i][2][r];
        float v3 = acc[i][3][r];
        float ss = v0 * v0 + v1 * v1 + v2 * v2 + v3 * v3;
        ss += __shfl_xor(ss, 1); ss += __shfl_xor(ss, 2);
        ss += __shfl_xor(ss, 4); ss += __shfl_xor(ss, 8);
        float rs = sq * rsqrtf(ss + 1e-6f);
        v0 *= rs; v1 *= rs; v2 *= rs; v3 *= rs;
        float o0 = v0 * cssn.x - v1 * cssn.y;
        float o1 = v1 * cssn.x + v0 * cssn.y;
        u16* trow = T + (size_t)(wm + i * 16 + rb + r) * 136 + wn + lr;
        trow[0]  = f2bf(o0); trow[16] = f2bf(o1);
        trow[32] = f2bf(v2); trow[48] = f2bf(v3);
      }
    __syncthreads();
    u16* dst = (part == 0) ? q : k;
    #pragma unroll
    for (int c = 0; c < 8; c++) {
      int chunk = c * 256 + tid;           // 2048 chunks of u16x8
      int ml = chunk >> 4, sub = chunk & 15;
      int m = m0 + ml;
      int nidx = m / SDIM, sp = m - nidx * SDIM;
      int hl = sub >> 3, e0 = (sub & 7) * 8;
      u16x8 v = *(const u16x8*)&T[(size_t)ml * 136 + sub * 8];
      *(u16x8*)(dst + ((size_t)(nidx * NHEAD + hbase + hl) * SDIM + sp) * EDIM + e0) = v;
    }
  } else {
    #pragma unroll
    for (int i = 0; i < 4; i++)
      #pragma unroll
      for (int j = 0; j < 4; j++)
        #pragma unroll
        for (int r = 0; r < 4; r++)
          T[(size_t)(wn + j * 16 + lr) * 136 + (wm + i * 16 + rb + r)] = f2bf(acc[i][j][r]);
    __syncthreads();
    #pragma unroll
    for (int c = 0; c < 8; c++) {
      int chunk = c * 256 + tid;
      int nl = chunk >> 4, sub = chunk & 15;
      int hl = nl >> 6, e = nl & 63;
      int m = m0 + sub * 8;                // 576%8==0: no nidx straddle in a chunk
      int nidx = m / SDIM, hw = m - nidx * SDIM;
      u16x8 v = *(const u16x8*)&T[(size_t)nl * 136 + sub * 8];
      *(u16x8*)(vt + ((size_t)(nidx * NHEAD + hbase + hl) * EDIM + e) * SDIM + hw) = v;
    }
  }
}

// ---------------- MFMA flash attention v6: triple-buffer, 1 barrier/tile ----------
// Block = 4 waves x 48 q-rows. K/V staged via global_load_lds, 3 buffers,
// prefetch depth 2 (vmcnt(4) waits only the consumed tile; ~2 tiles in flight).
// ONE barrier per tile: STAGE(t+2) issued AFTER barrier t -> its target buffer
// (t+2)%3 == (t-1)%3 was last read in iter t-1, and barrier-t passage implies all
// waves finished iter t-1. setprio(1) wraps MFMA clusters (T5, m191 +4-7%).
__global__ __launch_bounds__(256, 2) void attn_mfma(const u16* __restrict__ q,
                                                    const u16* __restrict__ k,
                                                    const u16* __restrict__ vt,
                                                    u16* __restrict__ o) {
  __shared__ u16 kbuf[3][4096];            // [buf][64 s][64 e] (16B-chunk swizzled)
  __shared__ u16 vbuf[3][4096];            // [buf][64 e][64 s]
  __shared__ u16 p_lds[4][48][72];
  int L = blockIdx.x;
  int cid = (L & 7) * 72 + (L >> 3);       // 576 = 8 XCD x 72, bijective
  int nh_ = cid / 3;
  int qt = cid - nh_ * 3;
  int n = nh_ / NHEAD, h = nh_ - n * NHEAD;
  int tid = threadIdx.x;
  int wid = tid >> 6, lane = tid & 63;
  int lr = lane & 15, lg = lane >> 4;
  int qbase = qt * 192 + wid * 48;

  const u16* qp = q + ((size_t)nh_ * SDIM + qbase) * EDIM;
  bf16x8 qa[3][2];
  #pragma unroll
  for (int f = 0; f < 3; f++) {
    qa[f][0] = *(const bf16x8*)(qp + (size_t)(f * 16 + lr) * EDIM + lg * 8);
    qa[f][1] = *(const bf16x8*)(qp + (size_t)(f * 16 + lr) * EDIM + 32 + lg * 8);
  }
  const u16* kb = k + (size_t)nh_ * SDIM * EDIM;
  const u16* vb = vt + (size_t)nh_ * EDIM * SDIM;

  int srow = wid * 16 + (lane >> 3);
  int schunk = (lane & 7) ^ (lane >> 3);   // inverse-swizzled source chunk
  auto STAGE = [&](int buf, int s0) {
    #pragma unroll
    for (int is = 0; is < 2; is++) {
      int row = srow + is * 8;
      __builtin_amdgcn_global_load_lds(
          (const __attribute__((address_space(1))) unsigned int*)(kb + (size_t)(s0 + row) * EDIM + schunk * 8),
          (__attribute__((address_space(3))) unsigned int*)(&kbuf[buf][(size_t)(wid * 16 + is * 8 + (lane >> 3)) * 64 + (lane & 7) * 8]),
          16, 0, 0);
      __builtin_amdgcn_global_load_lds(
          (const __attribute__((address_space(1))) unsigned int*)(vb + (size_t)row * SDIM + s0 + schunk * 8),
          (__attribute__((address_space(3))) unsigned int*)(&vbuf[buf][(size_t)(wid * 16 + is * 8 + (lane >> 3)) * 64 + (lane & 7) * 8]),
          16, 0, 0);
    }
  };

  float psum[3] = {0.0f, 0.0f, 0.0f};
  f32x4 oacc[3][4] = {};

  STAGE(0, 0);
  STAGE(1, 64);
  #pragma unroll 1
  for (int kt = 0; kt < 9; kt++) {
    if (kt < 8) {
      asm volatile("s_waitcnt vmcnt(4)" ::: "memory");   // tile kt done; kt+1 in flight
    } else {
      asm volatile("s_waitcnt vmcnt(0)" ::: "memory");
    }
    __builtin_amdgcn_s_barrier();          // all waves' tile-kt data visible
    __builtin_amdgcn_sched_barrier(0);
    if (kt < 7) STAGE((kt + 2) % 3, (kt + 2) * 64);
    const u16* kl = kbuf[kt % 3];
    const u16* vl = vbuf[kt % 3];
    // ---- K fragments from LDS (conflict-free swizzled reads) ----
    bf16x8 kf[4][2];
    #pragma unroll
    for (int j = 0; j < 4; j++) {
      kf[j][0] = *(const bf16x8*)&kl[(j * 16 + lr) * 64 + ((lg       ^ (lr & 7)) * 8)];
      kf[j][1] = *(const bf16x8*)&kl[(j * 16 + lr) * 64 + (((lg + 4) ^ (lr & 7)) * 8)];
    }
    // ---- V fragments ----
    bf16x8 vf[2][4];
    #pragma unroll
    for (int ks = 0; ks < 2; ks++)
      #pragma unroll
      for (int et = 0; et < 4; et++)
        vf[ks][et] = *(const bf16x8*)&vl[(et * 16 + lr) * 64 + (((ks * 4 + lg) ^ (lr & 7)) * 8)];
    // ---- swapped QK^T + exp2 softmax (no max: |logit| <= 10·log2e) ----
    #pragma unroll
    for (int f = 0; f < 3; f++) {
      f32x4 sfr[4] = {};
      __builtin_amdgcn_s_setprio(1);
      #pragma unroll
      for (int j = 0; j < 4; j++) {
        sfr[j] = __builtin_amdgcn_mfma_f32_16x16x32_bf16(kf[j][0], qa[f][0], sfr[j], 0, 0, 0);
        sfr[j] = __builtin_amdgcn_mfma_f32_16x16x32_bf16(kf[j][1], qa[f][1], sfr[j], 0, 0, 0);
      }
      __builtin_amdgcn_s_setprio(0);
      float fs = 0.0f;
      #pragma unroll
      for (int j = 0; j < 4; j++) {
        float p0 = exp2f(sfr[j][0]);
        float p1 = exp2f(sfr[j][1]);
        float p2 = exp2f(sfr[j][2]);
        float p3 = exp2f(sfr[j][3]);
        unsigned w0 = cvt_pk_bf16(p0, p1);
        unsigned w1 = cvt_pk_bf16(p2, p3);
        *(unsigned*)&p_lds[wid][f * 16 + lr][j * 16 + lg * 4]     = w0;
        *(unsigned*)&p_lds[wid][f * 16 + lr][j * 16 + lg * 4 + 2] = w1;
        fs += (p0 + p1) + (p2 + p3);
      }
      psum[f] += fs;
    }
    // ---- PV ----
    __builtin_amdgcn_s_setprio(1);
    #pragma unroll
    for (int f = 0; f < 3; f++)
      #pragma unroll
      for (int ks = 0; ks < 2; ks++) {
        bf16x8 pa = *(const bf16x8*)&p_lds[wid][f * 16 + lr][ks * 32 + lg * 8];
        #pragma unroll
        for (int et = 0; et < 4; et++)
          oacc[f][et] = __builtin_amdgcn_mfma_f32_16x16x32_bf16(pa, vf[ks][et], oacc[f][et], 0, 0, 0);
      }
    __builtin_amdgcn_s_setprio(0);
    __builtin_amdgcn_sched_barrier(0);
  }
  // ---- epilogue ----
  u16* ob = o + ((size_t)n * SDIM + qbase) * CDIM + h * EDIM;
  #pragma unroll
  for (int f = 0; f < 3; f++) {
    float s = psum[f];
    s += __shfl_xor(s, 16);
    s += __shfl_xor(s, 32);
    float inv = 1.0f / s;
    #pragma unroll
    for (int r = 0; r < 4; r++) {
      float invr = __shfl(inv, lg * 4 + r);
      #pragma unroll
      for (int et = 0; et < 4; et++)
        ob[(size_t)(f * 16 + lg * 4 + r) * CDIM + et * 16 + lr] = f2bf(oacc[f][et][r] * invr);
    }
  }
}

// ---------------- out projection + skip, COALESCED via LDS transpose ----------------
__global__ __launch_bounds__(256) void gemm_proj(const u16* __restrict__ o,
                                                 const u16* __restrict__ wo,
                                                 const float* __restrict__ x,
                                                 float* __restrict__ out) {
  __shared__ __align__(16) char smem[128 * 132 * 4];   // 67.6 KB >= 64 KB staging
  u16* ldsA = (u16*)smem;
  u16* ldsB = (u16*)smem + 16384;
  f32x4 acc[4][4] = {};
  int tid = threadIdx.x;
  int m0, n0;
  swz_tile(blockIdx.x, m0, n0);
  gemm_bt_lds(o, wo, CDIM, m0, n0, tid, ldsA, ldsB, acc);
  int lane = tid & 63, wid = tid >> 6;
  int wm = (wid >> 1) * 64, wn = (wid & 1) * 64;
  int lr = lane & 15, rb = (lane >> 4) * 4;
  float* T = (float*)smem;                 // [128 jj][132 m]
  #pragma unroll
  for (int i = 0; i < 4; i++)
    #pragma unroll
    for (int j = 0; j < 4; j++)
      #pragma unroll
      for (int r = 0; r < 4; r++)
        T[(size_t)(wn + j * 16 + lr) * 132 + (wm + i * 16 + rb + r)] = acc[i][j][r];
  __syncthreads();
  #pragma unroll
  for (int c = 0; c < 16; c++) {
    int chunk = c * 256 + tid;             // 4096 chunks of float4
    int nl = chunk >> 5, sub = chunk & 31;
    int m = m0 + sub * 4;                  // 576%4==0: no straddle
    int nidx = m / SDIM, hw = m - nidx * SDIM;
    int b = nidx >> 3, t = nidx & 7;
    int jj = n0 + nl;
    size_t oi = ((size_t)(b * CDIM + jj) * TDIM + t) * SDIM + hw;
    float4 xv = *(const float4*)&x[oi];
    float4 tv = *(const float4*)&T[(size_t)nl * 132 + sub * 4];
    float4 ov;
    ov.x = tv.x + xv.x; ov.y = tv.y + xv.y;
    ov.z = tv.z + xv.z; ov.w = tv.w + xv.w;
    *(float4*)&out[oi] = ov;
  }
}

extern "C" void kernel_launch(void* const* d_in, const int* in_sizes, int n_in,
                              void* d_out, int out_size, void* d_ws, size_t ws_size,
                              hipStream_t stream) {
  const float* x      = (const float*)d_in[0];
  const float* pos    = (const float*)d_in[1];
  const float* cond   = (const float*)d_in[2];
  const float* norm_w = (const float*)d_in[3];
  const float* qkv_w  = (const float*)d_in[4];
  const float* scale  = (const float*)d_in[5];
  const float* out_w  = (const float*)d_in[6];
  const float* freqs  = (const float*)d_in[7];
  float* out = (float*)d_out;

  char* ws = (char*)d_ws;
  size_t off = 0;
  auto alloc = [&](size_t bytes) -> char* {
    char* p = ws + off;
    off = (off + bytes + 255) & ~(size_t)255;
    return p;
  };
  float* cs   = (float*)alloc(2 * CDIM * sizeof(float));
  u16* wq     = (u16*)alloc((size_t)QKVN * CDIM * 2);
  u16* wo     = (u16*)alloc((size_t)CDIM * CDIM * 2);
  u16* xn     = (u16*)alloc((size_t)MDIM * CDIM * 2);
  u16* qb     = (u16*)alloc((size_t)MDIM * CDIM * 2);
  u16* kb     = (u16*)alloc((size_t)MDIM * CDIM * 2);
  u16* vt     = (u16*)alloc((size_t)MDIM * CDIM * 2);
  u16* ob     = (u16*)alloc((size_t)MDIM * CDIM * 2);
  float2* trg = (float2*)alloc((size_t)2 * SDIM * NHEAD * 16 * sizeof(float2));

  prep_kernel<<<dim3(3174), dim3(256), 0, stream>>>(qkv_w, wq, out_w, wo,
                                                    cond, norm_w, cs, pos, freqs, trg);
  norm_kernel<<<dim3(SDIM / 16, NROW), dim3(16, 16), 0, stream>>>(x, cs, xn);
  gemm_qkv<<<dim3(8 * 9 * (QKVN / 128)), dim3(256), 0, stream>>>(xn, wq, trg, scale, qb, kb, vt);
  attn_mfma<<<dim3(576), dim3(256), 0, stream>>>(qb, kb, vt, ob);
  gemm_proj<<<dim3(8 * 9 * (CDIM / 128)), dim3(256), 0, stream>>>(ob, wo, x, out);
}

// Round 16
// 161.905 us; speedup vs baseline: 1.0319x; 1.0121x over previous
//
#include <hip/hip_runtime.h>
#include <hip/hip_bf16.h>

// ---- geometry (fixed by the problem) ----
#define CDIM 768
#define NHEAD 12
#define EDIM 64
#define TDIM 8
#define SDIM 576
#define NROW 16          // B*T
#define MDIM 9216        // NROW*SDIM
#define QKVN 2304

typedef __attribute__((ext_vector_type(4))) float f32x4;
typedef __bf16 bf16x8 __attribute__((ext_vector_type(8)));
typedef unsigned short u16;
typedef __attribute__((ext_vector_type(8))) unsigned short u16x8;

__device__ inline float bf2f(u16 u) {
  union { unsigned int i; float f; } x; x.i = ((unsigned int)u) << 16; return x.f;
}
__device__ inline u16 f2bf(float f) {
  union { float f; unsigned int i; } x; x.f = f;
  unsigned int i = x.i;
  return (u16)((i + 0x7FFFu + ((i >> 16) & 1u)) >> 16);
}
__device__ inline unsigned cvt_pk_bf16(float lo, float hi) {
  unsigned r;
  asm("v_cvt_pk_bf16_f32 %0, %1, %2" : "=v"(r) : "v"(lo), "v"(hi));
  return r;
}

// ---------------- cs = cond @ norm_w^T + 1  (2 x 768); tiny, must precede norm ----
__global__ __launch_bounds__(256) void cs_kernel(const float* __restrict__ cond,
                                                 const float* __restrict__ nw,
                                                 float* __restrict__ cs) {
  int idx = blockIdx.x * 256 + threadIdx.x;      // 0..1535
  int b = idx / CDIM, c = idx % CDIM;
  const float* cr = cond + (size_t)b * CDIM;
  const float* wr = nw + (size_t)c * CDIM;
  float s = 1.0f;
  for (int j = 0; j < CDIM; j += 4) {
    float4 a = *(const float4*)(cr + j);
    float4 w = *(const float4*)(wr + j);
    s = fmaf(a.x, w.x, s); s = fmaf(a.y, w.y, s);
    s = fmaf(a.z, w.z, s); s = fmaf(a.w, w.w, s);
  }
  cs[idx] = s;
}

// ---------------- norm + weight converts + trig table, ONE kernel ----------------
// bid sections (all multiples of 256 threads):
//   [0,576)      RMS-norm * cs -> xn  (the long pole; starts first)
//   [576,2304)   convert qkv_w -> wq
//   [2304,2880)  convert out_w -> wo
//   [2880,3744)  trig[(h*1152 + bs)*16 + j] = (cos,sin)(pos[bs][j>>3]*freqs[h][j&7])
__global__ __launch_bounds__(256) void norm_prep_kernel(const float* __restrict__ x,
                                                        const float* __restrict__ cs,
                                                        u16* __restrict__ xn,
                                                        const float* __restrict__ qkv_w,
                                                        u16* __restrict__ wq,
                                                        const float* __restrict__ out_w,
                                                        u16* __restrict__ wo,
                                                        const float* __restrict__ pos,
                                                        const float* __restrict__ freqs,
                                                        float2* __restrict__ trig) {
  __shared__ float xs[16][772];
  __shared__ float red[16][17];
  __shared__ float rfac[16];
  int bid = blockIdx.x;
  int tid = threadIdx.x;
  if (bid < 576) {
    int n = bid / 36;
    int hw0 = (bid - n * 36) * 16;
    int b = n >> 3, t = n & 7;
    int tx = tid & 15, ty = tid >> 4;
    const float* xb = x + ((size_t)b * CDIM * TDIM + t) * SDIM;
    float acc = 0.0f;
    for (int c = ty; c < CDIM; c += 16) {
      float v = xb[(size_t)c * (TDIM * SDIM) + hw0 + tx];
      xs[tx][c] = v;
      acc = fmaf(v, v, acc);
    }
    red[ty][tx] = acc;
    __syncthreads();
    if (ty == 0) {
      float s = 0.0f;
      #pragma unroll
      for (int j = 0; j < 16; j++) s += red[j][tx];
      rfac[tx] = rsqrtf(s * (1.0f / (float)CDIM) + 1e-6f);
    }
    __syncthreads();
    const float* csb = cs + (size_t)b * CDIM;
    #pragma unroll
    for (int i = 0; i < 6; i++) {
      int idx = i * 256 + tid;
      int row = idx / 96;
      int cseg = idx - row * 96;
      int c0 = cseg * 8;
      float rf = rfac[row];
      float4 a0 = *(const float4*)&xs[row][c0];
      float4 a1 = *(const float4*)&xs[row][c0 + 4];
      float4 w0 = *(const float4*)(csb + c0);
      float4 w1 = *(const float4*)(csb + c0 + 4);
      union { u16x8 v; unsigned u[4]; } ov;
      ov.u[0] = cvt_pk_bf16(a0.x * w0.x * rf, a0.y * w0.y * rf);
      ov.u[1] = cvt_pk_bf16(a0.z * w0.z * rf, a0.w * w0.w * rf);
      ov.u[2] = cvt_pk_bf16(a1.x * w1.x * rf, a1.y * w1.y * rf);
      ov.u[3] = cvt_pk_bf16(a1.z * w1.z * rf, a1.w * w1.w * rf);
      *(u16x8*)(xn + ((size_t)n * SDIM + hw0 + row) * CDIM + c0) = ov.v;
    }
  } else if (bid < 2304) {
    int i = (bid - 576) * 256 + tid;
    float4 v = *(const float4*)(qkv_w + (size_t)i * 4);
    union { unsigned long long d; unsigned u[2]; } pk;
    pk.u[0] = cvt_pk_bf16(v.x, v.y);
    pk.u[1] = cvt_pk_bf16(v.z, v.w);
    *(unsigned long long*)(wq + (size_t)i * 4) = pk.d;
  } else if (bid < 2880) {
    int i = (bid - 2304) * 256 + tid;
    float4 v = *(const float4*)(out_w + (size_t)i * 4);
    union { unsigned long long d; unsigned u[2]; } pk;
    pk.u[0] = cvt_pk_bf16(v.x, v.y);
    pk.u[1] = cvt_pk_bf16(v.z, v.w);
    *(unsigned long long*)(wo + (size_t)i * 4) = pk.d;
  } else {
    int idx = (bid - 2880) * 256 + tid;          // 0..221183 over (h, bs, j)
    int j = idx & 15;
    int hb = idx >> 4;                           // h*1152 + bs
    int h = hb / 1152;
    int bs = hb - h * 1152;
    float p = pos[(size_t)bs * 2 + (j >> 3)];
    float th = p * freqs[h * 8 + (j & 7)];
    float sn, cn;
    __sincosf(th, &sn, &cn);
    trig[idx] = make_float2(cn, sn);
  }
}

// ---------------- MFMA GEMM core: dbuf + counted vmcnt ----------------
__device__ __forceinline__ void gemm_bt_lds(const u16* __restrict__ A,
                                            const u16* __restrict__ B,
                                            int K, int m0, int n0, int tid,
                                            u16* ldsA, u16* ldsB,
                                            f32x4 acc[4][4]) {
  int lane = tid & 63;
  int wid = tid >> 6;
  int wm = (wid >> 1) * 64, wn = (wid & 1) * 64;
  int lr = lane & 15, lg = lane >> 4;
  const u16* gA = A + (size_t)(m0 + wid * 32 + (lane >> 3)) * K + (((lane & 7) ^ (lane >> 3)) * 8);
  const u16* gB = B + (size_t)(n0 + wid * 32 + (lane >> 3)) * K + (((lane & 7) ^ (lane >> 3)) * 8);
  u16* dA = ldsA + wid * 2048;
  u16* dB = ldsB + wid * 2048;
  auto STAGE = [&](int buf, int k0) {
    u16* dAb = dA + buf * 8192;
    u16* dBb = dB + buf * 8192;
    #pragma unroll
    for (int is = 0; is < 4; is++) {
      __builtin_amdgcn_global_load_lds(
          (const __attribute__((address_space(1))) unsigned int*)(gA + (size_t)(is * 8) * K + k0),
          (__attribute__((address_space(3))) unsigned int*)(dAb + is * 512),
          16, 0, 0);
      __builtin_amdgcn_global_load_lds(
          (const __attribute__((address_space(1))) unsigned int*)(gB + (size_t)(is * 8) * K + k0),
          (__attribute__((address_space(3))) unsigned int*)(dBb + is * 512),
          16, 0, 0);
    }
  };
  int nt = K >> 6;
  STAGE(0, 0);
  int cur = 0;
  #pragma unroll 1
  for (int t = 0; t < nt; t++) {
    if (t + 1 < nt) {
      STAGE(cur ^ 1, (t + 1) * 64);
      asm volatile("s_waitcnt vmcnt(8)" ::: "memory");
    } else {
      asm volatile("s_waitcnt vmcnt(0)" ::: "memory");
    }
    __builtin_amdgcn_s_barrier();
    __builtin_amdgcn_sched_barrier(0);
    const u16* lA = ldsA + cur * 8192;
    const u16* lB = ldsB + cur * 8192;
    #pragma unroll
    for (int kk = 0; kk < 2; kk++) {
      bf16x8 af[4], bfr[4];
      #pragma unroll
      for (int i = 0; i < 4; i++)
        af[i]  = *(const bf16x8*)&lA[(wm + i * 16 + lr) * 64 + (((lg + 4 * kk) ^ (lr & 7)) * 8)];
      #pragma unroll
      for (int j = 0; j < 4; j++)
        bfr[j] = *(const bf16x8*)&lB[(wn + j * 16 + lr) * 64 + (((lg + 4 * kk) ^ (lr & 7)) * 8)];
      #pragma unroll
      for (int i = 0; i < 4; i++)
        #pragma unroll
        for (int j = 0; j < 4; j++)
          acc[i][j] = __builtin_amdgcn_mfma_f32_16x16x32_bf16(af[i], bfr[j], acc[i][j], 0, 0, 0);
    }
    __builtin_amdgcn_sched_barrier(0);
    __builtin_amdgcn_s_barrier();
    __builtin_amdgcn_sched_barrier(0);
    cur ^= 1;
  }
}

// XCD-chunk swizzle: grid = 8 XCD * 9 m-blocks * NBLK n-blocks (bijective).
__device__ __forceinline__ void swz_tile(int L, int& m0, int& n0) {
  int xcd = L & 7, loc = L >> 3;
  int nblk = loc / 9, mloc = loc - nblk * 9;
  m0 = (xcd * 9 + mloc) * 128;
  n0 = nblk * 128;
}

// ---------------- QKV GEMM: fused cos-norm+RoPE (table), coalesced stores ----------
__global__ __launch_bounds__(256) void gemm_qkv(const u16* __restrict__ xn,
                                                const u16* __restrict__ wq,
                                                const float2* __restrict__ trig,
                                                const float* __restrict__ scale,
                                                u16* __restrict__ q,
                                                u16* __restrict__ k,
                                                u16* __restrict__ vt) {
  __shared__ u16 smem[32768];              // 64 KB: staging dbuf; reused by epilogue
  u16* ldsA = smem;
  u16* ldsB = smem + 16384;
  f32x4 acc[4][4] = {};
  int tid = threadIdx.x;
  int m0, n0;
  swz_tile(blockIdx.x, m0, n0);
  gemm_bt_lds(xn, wq, CDIM, m0, n0, tid, ldsA, ldsB, acc);
  int lane = tid & 63, wid = tid >> 6;
  int wm = (wid >> 1) * 64, wn = (wid & 1) * 64;
  int lr = lane & 15, rb = (lane >> 4) * 4;
  int part = n0 / CDIM;                    // block-uniform
  int hbase = (n0 - part * CDIM) >> 6;     // block-uniform head base (2 heads/block)
  // block-uniform row split: m0 % 576 (both multiples of 64 -> no wrap in a 64-slab)
  int nidx_b = m0 / SDIM, rm0 = m0 - nidx_b * SDIM;
  u16* T = smem;                           // [128][136]
  if (part < 2) {
    int h = hbase + (wn >> 6);             // wave-uniform head
    float sq = sqrtf(scale[h]) * (part == 0 ? 1.44269504f : 1.0f);
    const float2* tg = trig + (size_t)h * 1152 * 16;
    #pragma unroll
    for (int i = 0; i < 4; i++)
      #pragma unroll
      for (int r = 0; r < 4; r++) {
        int off = wm + i * 16 + rb + r;    // 0..127; slab never crosses 576
        int sp = rm0 + off;
        int nidx = nidx_b + (sp >= SDIM);
        sp -= (sp >= SDIM) ? SDIM : 0;
        int b = nidx >> 3;
        float2 cssn = tg[((size_t)b * SDIM + sp) * 16 + lr];
        float v0 = acc[i][0][r];
        float v1 = acc[i][1][r];
        float v2 = acc[i][2][r];
        float v3 = acc[i][3][r];
        float ss = v0 * v0 + v1 * v1 + v2 * v2 + v3 * v3;
        ss += __shfl_xor(ss, 1); ss += __shfl_xor(ss, 2);
        ss += __shfl_xor(ss, 4); ss += __shfl_xor(ss, 8);
        float rs = sq * rsqrtf(ss + 1e-6f);
        v0 *= rs; v1 *= rs; v2 *= rs; v3 *= rs;
        float o0 = v0 * cssn.x - v1 * cssn.y;
        float o1 = v1 * cssn.x + v0 * cssn.y;
        u16* trow = T + (size_t)off * 136 + wn + lr;
        trow[0]  = f2bf(o0); trow[16] = f2bf(o1);
        trow[32] = f2bf(v2); trow[48] = f2bf(v3);
      }
    __syncthreads();
    u16* dst = (part == 0) ? q : k;
    #pragma unroll
    for (int c = 0; c < 8; c++) {
      int chunk = c * 256 + tid;           // 2048 chunks of u16x8
      int ml = chunk >> 4, sub = chunk & 15;
      int sp = rm0 + ml;
      int nidx = nidx_b + (sp >= SDIM);
      sp -= (sp >= SDIM) ? SDIM : 0;
      int hl = sub >> 3, e0 = (sub & 7) * 8;
      u16x8 v = *(const u16x8*)&T[(size_t)ml * 136 + sub * 8];
      *(u16x8*)(dst + ((size_t)(nidx * NHEAD + hbase + hl) * SDIM + sp) * EDIM + e0) = v;
    }
  } else {
    #pragma unroll
    for (int i = 0; i < 4; i++)
      #pragma unroll
      for (int j = 0; j < 4; j++)
        #pragma unroll
        for (int r = 0; r < 4; r++)
          T[(size_t)(wn + j * 16 + lr) * 136 + (wm + i * 16 + rb + r)] = f2bf(acc[i][j][r]);
    __syncthreads();
    #pragma unroll
    for (int c = 0; c < 8; c++) {
      int chunk = c * 256 + tid;
      int nl = chunk >> 4, sub = chunk & 15;
      int hl = nl >> 6, e = nl & 63;
      int hw = rm0 + sub * 8;              // 576%8==0: chunk never straddles
      int nidx = nidx_b + (hw >= SDIM);
      hw -= (hw >= SDIM) ? SDIM : 0;
      u16x8 v = *(const u16x8*)&T[(size_t)nl * 136 + sub * 8];
      *(u16x8*)(vt + ((size_t)(nidx * NHEAD + hbase + hl) * EDIM + e) * SDIM + hw) = v;
    }
  }
}

// ---------------- MFMA flash attention v6: triple-buffer, 1 barrier/tile ----------
__global__ __launch_bounds__(256, 2) void attn_mfma(const u16* __restrict__ q,
                                                    const u16* __restrict__ k,
                                                    const u16* __restrict__ vt,
                                                    u16* __restrict__ o) {
  __shared__ u16 kbuf[3][4096];            // [buf][64 s][64 e] (16B-chunk swizzled)
  __shared__ u16 vbuf[3][4096];            // [buf][64 e][64 s]
  __shared__ u16 p_lds[4][48][72];
  int L = blockIdx.x;
  int cid = (L & 7) * 72 + (L >> 3);       // 576 = 8 XCD x 72, bijective
  int nh_ = cid / 3;
  int qt = cid - nh_ * 3;
  int n = nh_ / NHEAD, h = nh_ - n * NHEAD;
  int tid = threadIdx.x;
  int wid = tid >> 6, lane = tid & 63;
  int lr = lane & 15, lg = lane >> 4;
  int qbase = qt * 192 + wid * 48;

  const u16* qp = q + ((size_t)nh_ * SDIM + qbase) * EDIM;
  bf16x8 qa[3][2];
  #pragma unroll
  for (int f = 0; f < 3; f++) {
    qa[f][0] = *(const bf16x8*)(qp + (size_t)(f * 16 + lr) * EDIM + lg * 8);
    qa[f][1] = *(const bf16x8*)(qp + (size_t)(f * 16 + lr) * EDIM + 32 + lg * 8);
  }
  const u16* kb = k + (size_t)nh_ * SDIM * EDIM;
  const u16* vb = vt + (size_t)nh_ * EDIM * SDIM;

  int srow = wid * 16 + (lane >> 3);
  int schunk = (lane & 7) ^ (lane >> 3);   // inverse-swizzled source chunk
  auto STAGE = [&](int buf, int s0) {
    #pragma unroll
    for (int is = 0; is < 2; is++) {
      int row = srow + is * 8;
      __builtin_amdgcn_global_load_lds(
          (const __attribute__((address_space(1))) unsigned int*)(kb + (size_t)(s0 + row) * EDIM + schunk * 8),
          (__attribute__((address_space(3))) unsigned int*)(&kbuf[buf][(size_t)(wid * 16 + is * 8 + (lane >> 3)) * 64 + (lane & 7) * 8]),
          16, 0, 0);
      __builtin_amdgcn_global_load_lds(
          (const __attribute__((address_space(1))) unsigned int*)(vb + (size_t)row * SDIM + s0 + schunk * 8),
          (__attribute__((address_space(3))) unsigned int*)(&vbuf[buf][(size_t)(wid * 16 + is * 8 + (lane >> 3)) * 64 + (lane & 7) * 8]),
          16, 0, 0);
    }
  };

  float psum[3] = {0.0f, 0.0f, 0.0f};
  f32x4 oacc[3][4] = {};

  STAGE(0, 0);
  STAGE(1, 64);
  #pragma unroll 1
  for (int kt = 0; kt < 9; kt++) {
    if (kt < 8) {
      asm volatile("s_waitcnt vmcnt(4)" ::: "memory");   // tile kt done; kt+1 in flight
    } else {
      asm volatile("s_waitcnt vmcnt(0)" ::: "memory");
    }
    __builtin_amdgcn_s_barrier();          // all waves' tile-kt data visible
    __builtin_amdgcn_sched_barrier(0);
    if (kt < 7) STAGE((kt + 2) % 3, (kt + 2) * 64);
    const u16* kl = kbuf[kt % 3];
    const u16* vl = vbuf[kt % 3];
    bf16x8 kf[4][2];
    #pragma unroll
    for (int j = 0; j < 4; j++) {
      kf[j][0] = *(const bf16x8*)&kl[(j * 16 + lr) * 64 + ((lg       ^ (lr & 7)) * 8)];
      kf[j][1] = *(const bf16x8*)&kl[(j * 16 + lr) * 64 + (((lg + 4) ^ (lr & 7)) * 8)];
    }
    bf16x8 vf[2][4];
    #pragma unroll
    for (int ks = 0; ks < 2; ks++)
      #pragma unroll
      for (int et = 0; et < 4; et++)
        vf[ks][et] = *(const bf16x8*)&vl[(et * 16 + lr) * 64 + (((ks * 4 + lg) ^ (lr & 7)) * 8)];
    // ---- swapped QK^T + exp2 softmax (no max: |logit| <= 10·log2e) ----
    #pragma unroll
    for (int f = 0; f < 3; f++) {
      f32x4 sfr[4] = {};
      __builtin_amdgcn_s_setprio(1);
      #pragma unroll
      for (int j = 0; j < 4; j++) {
        sfr[j] = __builtin_amdgcn_mfma_f32_16x16x32_bf16(kf[j][0], qa[f][0], sfr[j], 0, 0, 0);
        sfr[j] = __builtin_amdgcn_mfma_f32_16x16x32_bf16(kf[j][1], qa[f][1], sfr[j], 0, 0, 0);
      }
      __builtin_amdgcn_s_setprio(0);
      float fs = 0.0f;
      #pragma unroll
      for (int j = 0; j < 4; j++) {
        float p0 = exp2f(sfr[j][0]);
        float p1 = exp2f(sfr[j][1]);
        float p2 = exp2f(sfr[j][2]);
        float p3 = exp2f(sfr[j][3]);
        unsigned w0 = cvt_pk_bf16(p0, p1);
        unsigned w1 = cvt_pk_bf16(p2, p3);
        *(unsigned*)&p_lds[wid][f * 16 + lr][j * 16 + lg * 4]     = w0;
        *(unsigned*)&p_lds[wid][f * 16 + lr][j * 16 + lg * 4 + 2] = w1;
        fs += (p0 + p1) + (p2 + p3);
      }
      psum[f] += fs;
    }
    // ---- PV ----
    __builtin_amdgcn_s_setprio(1);
    #pragma unroll
    for (int f = 0; f < 3; f++)
      #pragma unroll
      for (int ks = 0; ks < 2; ks++) {
        bf16x8 pa = *(const bf16x8*)&p_lds[wid][f * 16 + lr][ks * 32 + lg * 8];
        #pragma unroll
        for (int et = 0; et < 4; et++)
          oacc[f][et] = __builtin_amdgcn_mfma_f32_16x16x32_bf16(pa, vf[ks][et], oacc[f][et], 0, 0, 0);
      }
    __builtin_amdgcn_s_setprio(0);
    __builtin_amdgcn_sched_barrier(0);
  }
  // ---- epilogue ----
  u16* ob = o + ((size_t)n * SDIM + qbase) * CDIM + h * EDIM;
  #pragma unroll
  for (int f = 0; f < 3; f++) {
    float s = psum[f];
    s += __shfl_xor(s, 16);
    s += __shfl_xor(s, 32);
    float inv = 1.0f / s;
    #pragma unroll
    for (int r = 0; r < 4; r++) {
      float invr = __shfl(inv, lg * 4 + r);
      #pragma unroll
      for (int et = 0; et < 4; et++)
        ob[(size_t)(f * 16 + lg * 4 + r) * CDIM + et * 16 + lr] = f2bf(oacc[f][et][r] * invr);
    }
  }
}

// ---------------- out projection + skip, COALESCED via LDS transpose ----------------
__global__ __launch_bounds__(256) void gemm_proj(const u16* __restrict__ o,
                                                 const u16* __restrict__ wo,
                                                 const float* __restrict__ x,
                                                 float* __restrict__ out) {
  __shared__ __align__(16) char smem[128 * 132 * 4];   // 67.6 KB >= 64 KB staging
  u16* ldsA = (u16*)smem;
  u16* ldsB = (u16*)smem + 16384;
  f32x4 acc[4][4] = {};
  int tid = threadIdx.x;
  int m0, n0;
  swz_tile(blockIdx.x, m0, n0);
  gemm_bt_lds(o, wo, CDIM, m0, n0, tid, ldsA, ldsB, acc);
  int lane = tid & 63, wid = tid >> 6;
  int wm = (wid >> 1) * 64, wn = (wid & 1) * 64;
  int lr = lane & 15, rb = (lane >> 4) * 4;
  int nidx_b = m0 / SDIM, rm0 = m0 - nidx_b * SDIM;
  float* T = (float*)smem;                 // [128 jj][132 m]
  #pragma unroll
  for (int i = 0; i < 4; i++)
    #pragma unroll
    for (int j = 0; j < 4; j++)
      #pragma unroll
      for (int r = 0; r < 4; r++)
        T[(size_t)(wn + j * 16 + lr) * 132 + (wm + i * 16 + rb + r)] = acc[i][j][r];
  __syncthreads();
  #pragma unroll
  for (int c = 0; c < 16; c++) {
    int chunk = c * 256 + tid;             // 4096 chunks of float4
    int nl = chunk >> 5, sub = chunk & 31;
    int hw = rm0 + sub * 4;                // 576%4==0: no straddle
    int nidx = nidx_b + (hw >= SDIM);
    hw -= (hw >= SDIM) ? SDIM : 0;
    int b = nidx >> 3, t = nidx & 7;
    int jj = n0 + nl;
    size_t oi = ((size_t)(b * CDIM + jj) * TDIM + t) * SDIM + hw;
    float4 xv = *(const float4*)&x[oi];
    float4 tv = *(const float4*)&T[(size_t)nl * 132 + sub * 4];
    float4 ov;
    ov.x = tv.x + xv.x; ov.y = tv.y + xv.y;
    ov.z = tv.z + xv.z; ov.w = tv.w + xv.w;
    *(float4*)&out[oi] = ov;
  }
}

extern "C" void kernel_launch(void* const* d_in, const int* in_sizes, int n_in,
                              void* d_out, int out_size, void* d_ws, size_t ws_size,
                              hipStream_t stream) {
  const float* x      = (const float*)d_in[0];
  const float* pos    = (const float*)d_in[1];
  const float* cond   = (const float*)d_in[2];
  const float* norm_w = (const float*)d_in[3];
  const float* qkv_w  = (const float*)d_in[4];
  const float* scale  = (const float*)d_in[5];
  const float* out_w  = (const float*)d_in[6];
  const float* freqs  = (const float*)d_in[7];
  float* out = (float*)d_out;

  char* ws = (char*)d_ws;
  size_t off = 0;
  auto alloc = [&](size_t bytes) -> char* {
    char* p = ws + off;
    off = (off + bytes + 255) & ~(size_t)255;
    return p;
  };
  float* cs   = (float*)alloc(2 * CDIM * sizeof(float));
  u16* wq     = (u16*)alloc((size_t)QKVN * CDIM * 2);
  u16* wo     = (u16*)alloc((size_t)CDIM * CDIM * 2);
  u16* xn     = (u16*)alloc((size_t)MDIM * CDIM * 2);
  u16* qb     = (u16*)alloc((size_t)MDIM * CDIM * 2);
  u16* kb     = (u16*)alloc((size_t)MDIM * CDIM * 2);
  u16* vt     = (u16*)alloc((size_t)MDIM * CDIM * 2);
  u16* ob     = (u16*)alloc((size_t)MDIM * CDIM * 2);
  float2* trg = (float2*)alloc((size_t)NHEAD * 2 * SDIM * 16 * sizeof(float2));

  cs_kernel<<<dim3(6), dim3(256), 0, stream>>>(cond, norm_w, cs);
  norm_prep_kernel<<<dim3(3744), dim3(256), 0, stream>>>(x, cs, xn, qkv_w, wq,
                                                         out_w, wo, pos, freqs, trg);
  gemm_qkv<<<dim3(8 * 9 * (QKVN / 128)), dim3(256), 0, stream>>>(xn, wq, trg, scale, qb, kb, vt);
  attn_mfma<<<dim3(576), dim3(256), 0, stream>>>(qb, kb, vt, ob);
  gemm_proj<<<dim3(8 * 9 * (CDIM / 128)), dim3(256), 0, stream>>>(ob, wo, x, out);
}

// Round 17
// 150.567 us; speedup vs baseline: 1.1096x; 1.0753x over previous
//
#include <hip/hip_runtime.h>
#include <hip/hip_bf16.h>

// ---- geometry (fixed by the problem) ----
#define CDIM 768
#define NHEAD 12
#define EDIM 64
#define TDIM 8
#define SDIM 576
#define NROW 16          // B*T
#define MDIM 9216        // NROW*SDIM
#define QKVN 2304

typedef __attribute__((ext_vector_type(4))) float f32x4;
typedef __bf16 bf16x8 __attribute__((ext_vector_type(8)));
typedef unsigned short u16;
typedef __attribute__((ext_vector_type(8))) unsigned short u16x8;

__device__ inline float bf2f(u16 u) {
  union { unsigned int i; float f; } x; x.i = ((unsigned int)u) << 16; return x.f;
}
__device__ inline u16 f2bf(float f) {
  union { float f; unsigned int i; } x; x.f = f;
  unsigned int i = x.i;
  return (u16)((i + 0x7FFFu + ((i >> 16) & 1u)) >> 16);
}
__device__ inline unsigned cvt_pk_bf16(float lo, float hi) {
  unsigned r;
  asm("v_cvt_pk_bf16_f32 %0, %1, %2" : "=v"(r) : "v"(lo), "v"(hi));
  return r;
}

// ---------------- cs = cond @ norm_w^T + 1, split-K x4 (24 blocks, ~2us) ----------
__global__ __launch_bounds__(256) void cs_kernel(const float* __restrict__ cond,
                                                 const float* __restrict__ nw,
                                                 float* __restrict__ cs) {
  int idx = blockIdx.x * 256 + threadIdx.x;      // 0..6143
  int out = idx >> 2, ks = idx & 3;              // out 0..1535
  int b = out / CDIM, c = out - b * CDIM;
  const float* cr = cond + (size_t)b * CDIM + ks * 192;
  const float* wr = nw + (size_t)c * CDIM + ks * 192;
  float s = 0.0f;
  #pragma unroll
  for (int j = 0; j < 192; j += 4) {
    float4 a = *(const float4*)(cr + j);
    float4 w = *(const float4*)(wr + j);
    s = fmaf(a.x, w.x, s); s = fmaf(a.y, w.y, s);
    s = fmaf(a.z, w.z, s); s = fmaf(a.w, w.w, s);
  }
  s += __shfl_xor(s, 1);
  s += __shfl_xor(s, 2);
  if (ks == 0) cs[out] = s + 1.0f;
}

// ---------------- norm + weight converts + trig table, ONE kernel ----------------
__global__ __launch_bounds__(256) void norm_prep_kernel(const float* __restrict__ x,
                                                        const float* __restrict__ cs,
                                                        u16* __restrict__ xn,
                                                        const float* __restrict__ qkv_w,
                                                        u16* __restrict__ wq,
                                                        const float* __restrict__ out_w,
                                                        u16* __restrict__ wo,
                                                        const float* __restrict__ pos,
                                                        const float* __restrict__ freqs,
                                                        float2* __restrict__ trig) {
  __shared__ float xs[16][772];
  __shared__ float red[16][17];
  __shared__ float rfac[16];
  int bid = blockIdx.x;
  int tid = threadIdx.x;
  if (bid < 576) {
    int n = bid / 36;
    int hw0 = (bid - n * 36) * 16;
    int b = n >> 3, t = n & 7;
    int tx = tid & 15, ty = tid >> 4;
    const float* xb = x + ((size_t)b * CDIM * TDIM + t) * SDIM;
    float acc = 0.0f;
    for (int c = ty; c < CDIM; c += 16) {
      float v = xb[(size_t)c * (TDIM * SDIM) + hw0 + tx];
      xs[tx][c] = v;
      acc = fmaf(v, v, acc);
    }
    red[ty][tx] = acc;
    __syncthreads();
    if (ty == 0) {
      float s = 0.0f;
      #pragma unroll
      for (int j = 0; j < 16; j++) s += red[j][tx];
      rfac[tx] = rsqrtf(s * (1.0f / (float)CDIM) + 1e-6f);
    }
    __syncthreads();
    const float* csb = cs + (size_t)b * CDIM;
    #pragma unroll
    for (int i = 0; i < 6; i++) {
      int idx = i * 256 + tid;
      int row = idx / 96;
      int cseg = idx - row * 96;
      int c0 = cseg * 8;
      float rf = rfac[row];
      float4 a0 = *(const float4*)&xs[row][c0];
      float4 a1 = *(const float4*)&xs[row][c0 + 4];
      float4 w0 = *(const float4*)(csb + c0);
      float4 w1 = *(const float4*)(csb + c0 + 4);
      union { u16x8 v; unsigned u[4]; } ov;
      ov.u[0] = cvt_pk_bf16(a0.x * w0.x * rf, a0.y * w0.y * rf);
      ov.u[1] = cvt_pk_bf16(a0.z * w0.z * rf, a0.w * w0.w * rf);
      ov.u[2] = cvt_pk_bf16(a1.x * w1.x * rf, a1.y * w1.y * rf);
      ov.u[3] = cvt_pk_bf16(a1.z * w1.z * rf, a1.w * w1.w * rf);
      *(u16x8*)(xn + ((size_t)n * SDIM + hw0 + row) * CDIM + c0) = ov.v;
    }
  } else if (bid < 2304) {
    int i = (bid - 576) * 256 + tid;
    float4 v = *(const float4*)(qkv_w + (size_t)i * 4);
    union { unsigned long long d; unsigned u[2]; } pk;
    pk.u[0] = cvt_pk_bf16(v.x, v.y);
    pk.u[1] = cvt_pk_bf16(v.z, v.w);
    *(unsigned long long*)(wq + (size_t)i * 4) = pk.d;
  } else if (bid < 2880) {
    int i = (bid - 2304) * 256 + tid;
    float4 v = *(const float4*)(out_w + (size_t)i * 4);
    union { unsigned long long d; unsigned u[2]; } pk;
    pk.u[0] = cvt_pk_bf16(v.x, v.y);
    pk.u[1] = cvt_pk_bf16(v.z, v.w);
    *(unsigned long long*)(wo + (size_t)i * 4) = pk.d;
  } else {
    int idx = (bid - 2880) * 256 + tid;          // 0..221183 over (h, bs, j)
    int j = idx & 15;
    int hb = idx >> 4;                           // h*1152 + bs
    int h = hb / 1152;
    int bs = hb - h * 1152;
    float p = pos[(size_t)bs * 2 + (j >> 3)];
    float th = p * freqs[h * 8 + (j & 7)];
    float sn, cn;
    __sincosf(th, &sn, &cn);
    trig[idx] = make_float2(cn, sn);
  }
}

// ---------------- MFMA GEMM core (128x128, 4 waves): dbuf + counted vmcnt --------
__device__ __forceinline__ void gemm_bt_lds(const u16* __restrict__ A,
                                            const u16* __restrict__ B,
                                            int K, int m0, int n0, int tid,
                                            u16* ldsA, u16* ldsB,
                                            f32x4 acc[4][4]) {
  int lane = tid & 63;
  int wid = tid >> 6;
  int wm = (wid >> 1) * 64, wn = (wid & 1) * 64;
  int lr = lane & 15, lg = lane >> 4;
  const u16* gA = A + (size_t)(m0 + wid * 32 + (lane >> 3)) * K + (((lane & 7) ^ (lane >> 3)) * 8);
  const u16* gB = B + (size_t)(n0 + wid * 32 + (lane >> 3)) * K + (((lane & 7) ^ (lane >> 3)) * 8);
  u16* dA = ldsA + wid * 2048;
  u16* dB = ldsB + wid * 2048;
  auto STAGE = [&](int buf, int k0) {
    u16* dAb = dA + buf * 8192;
    u16* dBb = dB + buf * 8192;
    #pragma unroll
    for (int is = 0; is < 4; is++) {
      __builtin_amdgcn_global_load_lds(
          (const __attribute__((address_space(1))) unsigned int*)(gA + (size_t)(is * 8) * K + k0),
          (__attribute__((address_space(3))) unsigned int*)(dAb + is * 512),
          16, 0, 0);
      __builtin_amdgcn_global_load_lds(
          (const __attribute__((address_space(1))) unsigned int*)(gB + (size_t)(is * 8) * K + k0),
          (__attribute__((address_space(3))) unsigned int*)(dBb + is * 512),
          16, 0, 0);
    }
  };
  int nt = K >> 6;
  STAGE(0, 0);
  int cur = 0;
  #pragma unroll 1
  for (int t = 0; t < nt; t++) {
    if (t + 1 < nt) {
      STAGE(cur ^ 1, (t + 1) * 64);
      asm volatile("s_waitcnt vmcnt(8)" ::: "memory");
    } else {
      asm volatile("s_waitcnt vmcnt(0)" ::: "memory");
    }
    __builtin_amdgcn_s_barrier();
    __builtin_amdgcn_sched_barrier(0);
    const u16* lA = ldsA + cur * 8192;
    const u16* lB = ldsB + cur * 8192;
    #pragma unroll
    for (int kk = 0; kk < 2; kk++) {
      bf16x8 af[4], bfr[4];
      #pragma unroll
      for (int i = 0; i < 4; i++)
        af[i]  = *(const bf16x8*)&lA[(wm + i * 16 + lr) * 64 + (((lg + 4 * kk) ^ (lr & 7)) * 8)];
      #pragma unroll
      for (int j = 0; j < 4; j++)
        bfr[j] = *(const bf16x8*)&lB[(wn + j * 16 + lr) * 64 + (((lg + 4 * kk) ^ (lr & 7)) * 8)];
      #pragma unroll
      for (int i = 0; i < 4; i++)
        #pragma unroll
        for (int j = 0; j < 4; j++)
          acc[i][j] = __builtin_amdgcn_mfma_f32_16x16x32_bf16(af[i], bfr[j], acc[i][j], 0, 0, 0);
    }
    __builtin_amdgcn_sched_barrier(0);
    __builtin_amdgcn_s_barrier();
    __builtin_amdgcn_sched_barrier(0);
    cur ^= 1;
  }
}

// XCD-chunk swizzle for the 128^2 grid (proj): 8 XCD * 9 m-blocks * nblk.
__device__ __forceinline__ void swz_tile(int L, int& m0, int& n0) {
  int xcd = L & 7, loc = L >> 3;
  int nblk = loc / 9, mloc = loc - nblk * 9;
  m0 = (xcd * 9 + mloc) * 128;
  n0 = nblk * 128;
}

// ---------------- QKV GEMM v2: 256x128 tile, 8 waves, fused RoPE epilogue --------
// Per CU per k-step: staging 48KB (vs 64KB at 128^2 x2blk) for the same 256 MFMA.
// Wave (wr,wc) owns 64x64 out; inner code identical to the proven 4-wave core.
__global__ __launch_bounds__(512) void gemm_qkv(const u16* __restrict__ xn,
                                                const u16* __restrict__ wq,
                                                const float2* __restrict__ trig,
                                                const float* __restrict__ scale,
                                                u16* __restrict__ q,
                                                u16* __restrict__ k,
                                                u16* __restrict__ vt) {
  __shared__ u16 smem[49152];              // 96KB: A dbuf 2x32KB + B dbuf 2x16KB
  u16* ldsA = smem;                        // [2][16384]
  u16* ldsB = smem + 32768;                // [2][8192]
  f32x4 acc[4][4] = {};
  int tid = threadIdx.x;
  int lane = tid & 63, wid = tid >> 6;     // 8 waves
  int wr = wid >> 1, wc = wid & 1;
  int wm = wr * 64, wn = wc * 64;
  int lr = lane & 15, lg = lane >> 4;
  int L = blockIdx.x;
  int cid = (L & 7) * 81 + (L >> 3);       // 648 = 8 XCD x 81, bijective
  int mb = cid / 18, nb = cid - mb * 18;   // m-major within XCD: A-panel reuse
  int m0 = mb * 256, n0 = nb * 128;

  const u16* gA = xn + (size_t)(m0 + wid * 32 + (lane >> 3)) * CDIM + (((lane & 7) ^ (lane >> 3)) * 8);
  const u16* gB = wq + (size_t)(n0 + wid * 16 + (lane >> 3)) * CDIM + (((lane & 7) ^ (lane >> 3)) * 8);
  u16* dA = ldsA + wid * 2048;             // rows [wid*32, wid*32+32)
  u16* dB = ldsB + wid * 1024;             // rows [wid*16, wid*16+16)
  auto STAGE = [&](int buf, int k0) {
    u16* dAb = dA + buf * 16384;
    u16* dBb = dB + buf * 8192;
    #pragma unroll
    for (int is = 0; is < 4; is++)
      __builtin_amdgcn_global_load_lds(
          (const __attribute__((address_space(1))) unsigned int*)(gA + (size_t)(is * 8) * CDIM + k0),
          (__attribute__((address_space(3))) unsigned int*)(dAb + is * 512),
          16, 0, 0);
    #pragma unroll
    for (int is = 0; is < 2; is++)
      __builtin_amdgcn_global_load_lds(
          (const __attribute__((address_space(1))) unsigned int*)(gB + (size_t)(is * 8) * CDIM + k0),
          (__attribute__((address_space(3))) unsigned int*)(dBb + is * 512),
          16, 0, 0);
  };
  STAGE(0, 0);
  int cur = 0;
  #pragma unroll 1
  for (int t = 0; t < 12; t++) {
    if (t + 1 < 12) {
      STAGE(cur ^ 1, (t + 1) * 64);
      asm volatile("s_waitcnt vmcnt(6)" ::: "memory");
    } else {
      asm volatile("s_waitcnt vmcnt(0)" ::: "memory");
    }
    __builtin_amdgcn_s_barrier();
    __builtin_amdgcn_sched_barrier(0);
    const u16* lA = ldsA + cur * 16384;
    const u16* lB = ldsB + cur * 8192;
    #pragma unroll
    for (int kk = 0; kk < 2; kk++) {
      bf16x8 af[4], bfr[4];
      #pragma unroll
      for (int i = 0; i < 4; i++)
        af[i]  = *(const bf16x8*)&lA[(wm + i * 16 + lr) * 64 + (((lg + 4 * kk) ^ (lr & 7)) * 8)];
      #pragma unroll
      for (int j = 0; j < 4; j++)
        bfr[j] = *(const bf16x8*)&lB[(wn + j * 16 + lr) * 64 + (((lg + 4 * kk) ^ (lr & 7)) * 8)];
      #pragma unroll
      for (int i = 0; i < 4; i++)
        #pragma unroll
        for (int j = 0; j < 4; j++)
          acc[i][j] = __builtin_amdgcn_mfma_f32_16x16x32_bf16(af[i], bfr[j], acc[i][j], 0, 0, 0);
    }
    __builtin_amdgcn_sched_barrier(0);
    __builtin_amdgcn_s_barrier();
    __builtin_amdgcn_sched_barrier(0);
    cur ^= 1;
  }

  int rb = lg * 4;
  int part = n0 / CDIM;                    // block-uniform (6 n-blocks per part)
  int hbase = (n0 - part * CDIM) >> 6;     // 2 heads per block
  int nidx_b = m0 / SDIM, rm0 = m0 - nidx_b * SDIM;   // 256-slab: <=1 boundary cross
  u16* T = smem;
  if (part < 2) {
    int h = hbase + wc;                    // wave-uniform head
    float sq = sqrtf(scale[h]) * (part == 0 ? 1.44269504f : 1.0f);
    const float2* tg = trig + (size_t)h * 1152 * 16;
    #pragma unroll
    for (int i = 0; i < 4; i++)
      #pragma unroll
      for (int r = 0; r < 4; r++) {
        int off = wm + i * 16 + rb + r;    // 0..255
        int sp = rm0 + off;
        int nidx = nidx_b + (sp >= SDIM);
        sp -= (sp >= SDIM) ? SDIM : 0;
        int b = nidx >> 3;
        float2 cssn = tg[((size_t)b * SDIM + sp) * 16 + lr];
        float v0 = acc[i][0][r];
        float v1 = acc[i][1][r];
        float v2 = acc[i][2][r];
        float v3 = acc[i][3][r];
        float ss = v0 * v0 + v1 * v1 + v2 * v2 + v3 * v3;
        ss += __shfl_xor(ss, 1); ss += __shfl_xor(ss, 2);
        ss += __shfl_xor(ss, 4); ss += __shfl_xor(ss, 8);
        float rs = sq * rsqrtf(ss + 1e-6f);
        v0 *= rs; v1 *= rs; v2 *= rs; v3 *= rs;
        float o0 = v0 * cssn.x - v1 * cssn.y;
        float o1 = v1 * cssn.x + v0 * cssn.y;
        u16* trow = T + (size_t)off * 136 + wn + lr;     // 256x136 = 69.6KB < 96KB
        trow[0]  = f2bf(o0); trow[16] = f2bf(o1);
        trow[32] = f2bf(v2); trow[48] = f2bf(v3);
      }
    __syncthreads();
    u16* dst = (part == 0) ? q : k;
    #pragma unroll
    for (int c = 0; c < 8; c++) {
      int chunk = c * 512 + tid;           // 4096 chunks of u16x8
      int ml = chunk >> 4, sub = chunk & 15;
      int sp = rm0 + ml;
      int nidx = nidx_b + (sp >= SDIM);
      sp -= (sp >= SDIM) ? SDIM : 0;
      int hl = sub >> 3, e0 = (sub & 7) * 8;
      u16x8 v = *(const u16x8*)&T[(size_t)ml * 136 + sub * 8];
      *(u16x8*)(dst + ((size_t)(nidx * NHEAD + hbase + hl) * SDIM + sp) * EDIM + e0) = v;
    }
  } else {
    #pragma unroll
    for (int i = 0; i < 4; i++)
      #pragma unroll
      for (int j = 0; j < 4; j++)
        #pragma unroll
        for (int r = 0; r < 4; r++)
          T[(size_t)(wn + j * 16 + lr) * 264 + (wm + i * 16 + rb + r)] = f2bf(acc[i][j][r]);
    __syncthreads();
    #pragma unroll
    for (int c = 0; c < 8; c++) {
      int chunk = c * 512 + tid;           // 4096 chunks of u16x8 (128n x 32 m-subs)
      int nl = chunk >> 5, sub = chunk & 31;
      int hl = nl >> 6, e = nl & 63;
      int hw = rm0 + sub * 8;
      int nidx = nidx_b + (hw >= SDIM);
      hw -= (hw >= SDIM) ? SDIM : 0;
      u16x8 v = *(const u16x8*)&T[(size_t)nl * 264 + sub * 8];
      *(u16x8*)(vt + ((size_t)(nidx * NHEAD + hbase + hl) * EDIM + e) * SDIM + hw) = v;
    }
  }
}

// ---------------- MFMA flash attention v6: triple-buffer, 1 barrier/tile ----------
__global__ __launch_bounds__(256, 2) void attn_mfma(const u16* __restrict__ q,
                                                    const u16* __restrict__ k,
                                                    const u16* __restrict__ vt,
                                                    u16* __restrict__ o) {
  __shared__ u16 kbuf[3][4096];
  __shared__ u16 vbuf[3][4096];
  __shared__ u16 p_lds[4][48][72];
  int L = blockIdx.x;
  int cid = (L & 7) * 72 + (L >> 3);
  int nh_ = cid / 3;
  int qt = cid - nh_ * 3;
  int n = nh_ / NHEAD, h = nh_ - n * NHEAD;
  int tid = threadIdx.x;
  int wid = tid >> 6, lane = tid & 63;
  int lr = lane & 15, lg = lane >> 4;
  int qbase = qt * 192 + wid * 48;

  const u16* qp = q + ((size_t)nh_ * SDIM + qbase) * EDIM;
  bf16x8 qa[3][2];
  #pragma unroll
  for (int f = 0; f < 3; f++) {
    qa[f][0] = *(const bf16x8*)(qp + (size_t)(f * 16 + lr) * EDIM + lg * 8);
    qa[f][1] = *(const bf16x8*)(qp + (size_t)(f * 16 + lr) * EDIM + 32 + lg * 8);
  }
  const u16* kb = k + (size_t)nh_ * SDIM * EDIM;
  const u16* vb = vt + (size_t)nh_ * EDIM * SDIM;

  int srow = wid * 16 + (lane >> 3);
  int schunk = (lane & 7) ^ (lane >> 3);
  auto STAGE = [&](int buf, int s0) {
    #pragma unroll
    for (int is = 0; is < 2; is++) {
      int row = srow + is * 8;
      __builtin_amdgcn_global_load_lds(
          (const __attribute__((address_space(1))) unsigned int*)(kb + (size_t)(s0 + row) * EDIM + schunk * 8),
          (__attribute__((address_space(3))) unsigned int*)(&kbuf[buf][(size_t)(wid * 16 + is * 8 + (lane >> 3)) * 64 + (lane & 7) * 8]),
          16, 0, 0);
      __builtin_amdgcn_global_load_lds(
          (const __attribute__((address_space(1))) unsigned int*)(vb + (size_t)row * SDIM + s0 + schunk * 8),
          (__attribute__((address_space(3))) unsigned int*)(&vbuf[buf][(size_t)(wid * 16 + is * 8 + (lane >> 3)) * 64 + (lane & 7) * 8]),
          16, 0, 0);
    }
  };

  float psum[3] = {0.0f, 0.0f, 0.0f};
  f32x4 oacc[3][4] = {};

  STAGE(0, 0);
  STAGE(1, 64);
  #pragma unroll 1
  for (int kt = 0; kt < 9; kt++) {
    if (kt < 8) {
      asm volatile("s_waitcnt vmcnt(4)" ::: "memory");
    } else {
      asm volatile("s_waitcnt vmcnt(0)" ::: "memory");
    }
    __builtin_amdgcn_s_barrier();
    __builtin_amdgcn_sched_barrier(0);
    if (kt < 7) STAGE((kt + 2) % 3, (kt + 2) * 64);
    const u16* kl = kbuf[kt % 3];
    const u16* vl = vbuf[kt % 3];
    bf16x8 kf[4][2];
    #pragma unroll
    for (int j = 0; j < 4; j++) {
      kf[j][0] = *(const bf16x8*)&kl[(j * 16 + lr) * 64 + ((lg       ^ (lr & 7)) * 8)];
      kf[j][1] = *(const bf16x8*)&kl[(j * 16 + lr) * 64 + (((lg + 4) ^ (lr & 7)) * 8)];
    }
    bf16x8 vf[2][4];
    #pragma unroll
    for (int ks = 0; ks < 2; ks++)
      #pragma unroll
      for (int et = 0; et < 4; et++)
        vf[ks][et] = *(const bf16x8*)&vl[(et * 16 + lr) * 64 + (((ks * 4 + lg) ^ (lr & 7)) * 8)];
    #pragma unroll
    for (int f = 0; f < 3; f++) {
      f32x4 sfr[4] = {};
      __builtin_amdgcn_s_setprio(1);
      #pragma unroll
      for (int j = 0; j < 4; j++) {
        sfr[j] = __builtin_amdgcn_mfma_f32_16x16x32_bf16(kf[j][0], qa[f][0], sfr[j], 0, 0, 0);
        sfr[j] = __builtin_amdgcn_mfma_f32_16x16x32_bf16(kf[j][1], qa[f][1], sfr[j], 0, 0, 0);
      }
      __builtin_amdgcn_s_setprio(0);
      float fs = 0.0f;
      #pragma unroll
      for (int j = 0; j < 4; j++) {
        float p0 = exp2f(sfr[j][0]);
        float p1 = exp2f(sfr[j][1]);
        float p2 = exp2f(sfr[j][2]);
        float p3 = exp2f(sfr[j][3]);
        unsigned w0 = cvt_pk_bf16(p0, p1);
        unsigned w1 = cvt_pk_bf16(p2, p3);
        *(unsigned*)&p_lds[wid][f * 16 + lr][j * 16 + lg * 4]     = w0;
        *(unsigned*)&p_lds[wid][f * 16 + lr][j * 16 + lg * 4 + 2] = w1;
        fs += (p0 + p1) + (p2 + p3);
      }
      psum[f] += fs;
    }
    __builtin_amdgcn_s_setprio(1);
    #pragma unroll
    for (int f = 0; f < 3; f++)
      #pragma unroll
      for (int ks = 0; ks < 2; ks++) {
        bf16x8 pa = *(const bf16x8*)&p_lds[wid][f * 16 + lr][ks * 32 + lg * 8];
        #pragma unroll
        for (int et = 0; et < 4; et++)
          oacc[f][et] = __builtin_amdgcn_mfma_f32_16x16x32_bf16(pa, vf[ks][et], oacc[f][et], 0, 0, 0);
      }
    __builtin_amdgcn_s_setprio(0);
    __builtin_amdgcn_sched_barrier(0);
  }
  u16* ob = o + ((size_t)n * SDIM + qbase) * CDIM + h * EDIM;
  #pragma unroll
  for (int f = 0; f < 3; f++) {
    float s = psum[f];
    s += __shfl_xor(s, 16);
    s += __shfl_xor(s, 32);
    float inv = 1.0f / s;
    #pragma unroll
    for (int r = 0; r < 4; r++) {
      float invr = __shfl(inv, lg * 4 + r);
      #pragma unroll
      for (int et = 0; et < 4; et++)
        ob[(size_t)(f * 16 + lg * 4 + r) * CDIM + et * 16 + lr] = f2bf(oacc[f][et][r] * invr);
    }
  }
}

// ---------------- out projection + skip, COALESCED via LDS transpose ----------------
__global__ __launch_bounds__(256) void gemm_proj(const u16* __restrict__ o,
                                                 const u16* __restrict__ wo,
                                                 const float* __restrict__ x,
                                                 float* __restrict__ out) {
  __shared__ __align__(16) char smem[128 * 132 * 4];
  u16* ldsA = (u16*)smem;
  u16* ldsB = (u16*)smem + 16384;
  f32x4 acc[4][4] = {};
  int tid = threadIdx.x;
  int m0, n0;
  swz_tile(blockIdx.x, m0, n0);
  gemm_bt_lds(o, wo, CDIM, m0, n0, tid, ldsA, ldsB, acc);
  int lane = tid & 63, wid = tid >> 6;
  int wm = (wid >> 1) * 64, wn = (wid & 1) * 64;
  int lr = lane & 15, rb = (lane >> 4) * 4;
  int nidx_b = m0 / SDIM, rm0 = m0 - nidx_b * SDIM;
  float* T = (float*)smem;
  #pragma unroll
  for (int i = 0; i < 4; i++)
    #pragma unroll
    for (int j = 0; j < 4; j++)
      #pragma unroll
      for (int r = 0; r < 4; r++)
        T[(size_t)(wn + j * 16 + lr) * 132 + (wm + i * 16 + rb + r)] = acc[i][j][r];
  __syncthreads();
  #pragma unroll
  for (int c = 0; c < 16; c++) {
    int chunk = c * 256 + tid;
    int nl = chunk >> 5, sub = chunk & 31;
    int hw = rm0 + sub * 4;
    int nidx = nidx_b + (hw >= SDIM);
    hw -= (hw >= SDIM) ? SDIM : 0;
    int b = nidx >> 3, t = nidx & 7;
    int jj = n0 + nl;
    size_t oi = ((size_t)(b * CDIM + jj) * TDIM + t) * SDIM + hw;
    float4 xv = *(const float4*)&x[oi];
    float4 tv = *(const float4*)&T[(size_t)nl * 132 + sub * 4];
    float4 ov;
    ov.x = tv.x + xv.x; ov.y = tv.y + xv.y;
    ov.z = tv.z + xv.z; ov.w = tv.w + xv.w;
    *(float4*)&out[oi] = ov;
  }
}

extern "C" void kernel_launch(void* const* d_in, const int* in_sizes, int n_in,
                              void* d_out, int out_size, void* d_ws, size_t ws_size,
                              hipStream_t stream) {
  const float* x      = (const float*)d_in[0];
  const float* pos    = (const float*)d_in[1];
  const float* cond   = (const float*)d_in[2];
  const float* norm_w = (const float*)d_in[3];
  const float* qkv_w  = (const float*)d_in[4];
  const float* scale  = (const float*)d_in[5];
  const float* out_w  = (const float*)d_in[6];
  const float* freqs  = (const float*)d_in[7];
  float* out = (float*)d_out;

  char* ws = (char*)d_ws;
  size_t off = 0;
  auto alloc = [&](size_t bytes) -> char* {
    char* p = ws + off;
    off = (off + bytes + 255) & ~(size_t)255;
    return p;
  };
  float* cs   = (float*)alloc(2 * CDIM * sizeof(float));
  u16* wq     = (u16*)alloc((size_t)QKVN * CDIM * 2);
  u16* wo     = (u16*)alloc((size_t)CDIM * CDIM * 2);
  u16* xn     = (u16*)alloc((size_t)MDIM * CDIM * 2);
  u16* qb     = (u16*)alloc((size_t)MDIM * CDIM * 2);
  u16* kb     = (u16*)alloc((size_t)MDIM * CDIM * 2);
  u16* vt     = (u16*)alloc((size_t)MDIM * CDIM * 2);
  u16* ob     = (u16*)alloc((size_t)MDIM * CDIM * 2);
  float2* trg = (float2*)alloc((size_t)NHEAD * 2 * SDIM * 16 * sizeof(float2));

  cs_kernel<<<dim3(24), dim3(256), 0, stream>>>(cond, norm_w, cs);
  norm_prep_kernel<<<dim3(3744), dim3(256), 0, stream>>>(x, cs, xn, qkv_w, wq,
                                                         out_w, wo, pos, freqs, trg);
  gemm_qkv<<<dim3(648), dim3(512), 0, stream>>>(xn, wq, trg, scale, qb, kb, vt);
  attn_mfma<<<dim3(576), dim3(256), 0, stream>>>(qb, kb, vt, ob);
  gemm_proj<<<dim3(8 * 9 * (CDIM / 128)), dim3(256), 0, stream>>>(ob, wo, x, out);
}

// Round 18
// 143.162 us; speedup vs baseline: 1.1670x; 1.0517x over previous
//
#include <hip/hip_runtime.h>
#include <hip/hip_bf16.h>

// ---- geometry (fixed by the problem) ----
#define CDIM 768
#define NHEAD 12
#define EDIM 64
#define TDIM 8
#define SDIM 576
#define NROW 16          // B*T
#define MDIM 9216        // NROW*SDIM
#define QKVN 2304

typedef __attribute__((ext_vector_type(4))) float f32x4;
typedef __bf16 bf16x8 __attribute__((ext_vector_type(8)));
typedef unsigned short u16;
typedef __attribute__((ext_vector_type(8))) unsigned short u16x8;

__device__ inline float bf2f(u16 u) {
  union { unsigned int i; float f; } x; x.i = ((unsigned int)u) << 16; return x.f;
}
__device__ inline u16 f2bf(float f) {
  union { float f; unsigned int i; } x; x.f = f;
  unsigned int i = x.i;
  return (u16)((i + 0x7FFFu + ((i >> 16) & 1u)) >> 16);
}
__device__ inline unsigned cvt_pk_bf16(float lo, float hi) {
  unsigned r;
  asm("v_cvt_pk_bf16_f32 %0, %1, %2" : "=v"(r) : "v"(lo), "v"(hi));
  return r;
}

// ---------------- cs = cond @ norm_w^T + 1, split-K x4 (24 blocks, ~2us) ----------
__global__ __launch_bounds__(256) void cs_kernel(const float* __restrict__ cond,
                                                 const float* __restrict__ nw,
                                                 float* __restrict__ cs) {
  int idx = blockIdx.x * 256 + threadIdx.x;      // 0..6143
  int out = idx >> 2, ks = idx & 3;              // out 0..1535
  int b = out / CDIM, c = out - b * CDIM;
  const float* cr = cond + (size_t)b * CDIM + ks * 192;
  const float* wr = nw + (size_t)c * CDIM + ks * 192;
  float s = 0.0f;
  #pragma unroll
  for (int j = 0; j < 192; j += 4) {
    float4 a = *(const float4*)(cr + j);
    float4 w = *(const float4*)(wr + j);
    s = fmaf(a.x, w.x, s); s = fmaf(a.y, w.y, s);
    s = fmaf(a.z, w.z, s); s = fmaf(a.w, w.w, s);
  }
  s += __shfl_xor(s, 1);
  s += __shfl_xor(s, 2);
  if (ks == 0) cs[out] = s + 1.0f;
}

// ---------------- norm + weight converts + trig table, ONE kernel ----------------
__global__ __launch_bounds__(256) void norm_prep_kernel(const float* __restrict__ x,
                                                        const float* __restrict__ cs,
                                                        u16* __restrict__ xn,
                                                        const float* __restrict__ qkv_w,
                                                        u16* __restrict__ wq,
                                                        const float* __restrict__ out_w,
                                                        u16* __restrict__ wo,
                                                        const float* __restrict__ pos,
                                                        const float* __restrict__ freqs,
                                                        float2* __restrict__ trig) {
  __shared__ float xs[16][772];
  __shared__ float red[16][17];
  __shared__ float rfac[16];
  int bid = blockIdx.x;
  int tid = threadIdx.x;
  if (bid < 576) {
    int n = bid / 36;
    int hw0 = (bid - n * 36) * 16;
    int b = n >> 3, t = n & 7;
    int tx = tid & 15, ty = tid >> 4;
    const float* xb = x + ((size_t)b * CDIM * TDIM + t) * SDIM;
    float acc = 0.0f;
    for (int c = ty; c < CDIM; c += 16) {
      float v = xb[(size_t)c * (TDIM * SDIM) + hw0 + tx];
      xs[tx][c] = v;
      acc = fmaf(v, v, acc);
    }
    red[ty][tx] = acc;
    __syncthreads();
    if (ty == 0) {
      float s = 0.0f;
      #pragma unroll
      for (int j = 0; j < 16; j++) s += red[j][tx];
      rfac[tx] = rsqrtf(s * (1.0f / (float)CDIM) + 1e-6f);
    }
    __syncthreads();
    const float* csb = cs + (size_t)b * CDIM;
    #pragma unroll
    for (int i = 0; i < 6; i++) {
      int idx = i * 256 + tid;
      int row = idx / 96;
      int cseg = idx - row * 96;
      int c0 = cseg * 8;
      float rf = rfac[row];
      float4 a0 = *(const float4*)&xs[row][c0];
      float4 a1 = *(const float4*)&xs[row][c0 + 4];
      float4 w0 = *(const float4*)(csb + c0);
      float4 w1 = *(const float4*)(csb + c0 + 4);
      union { u16x8 v; unsigned u[4]; } ov;
      ov.u[0] = cvt_pk_bf16(a0.x * w0.x * rf, a0.y * w0.y * rf);
      ov.u[1] = cvt_pk_bf16(a0.z * w0.z * rf, a0.w * w0.w * rf);
      ov.u[2] = cvt_pk_bf16(a1.x * w1.x * rf, a1.y * w1.y * rf);
      ov.u[3] = cvt_pk_bf16(a1.z * w1.z * rf, a1.w * w1.w * rf);
      *(u16x8*)(xn + ((size_t)n * SDIM + hw0 + row) * CDIM + c0) = ov.v;
    }
  } else if (bid < 2304) {
    int i = (bid - 576) * 256 + tid;
    float4 v = *(const float4*)(qkv_w + (size_t)i * 4);
    union { unsigned long long d; unsigned u[2]; } pk;
    pk.u[0] = cvt_pk_bf16(v.x, v.y);
    pk.u[1] = cvt_pk_bf16(v.z, v.w);
    *(unsigned long long*)(wq + (size_t)i * 4) = pk.d;
  } else if (bid < 2880) {
    int i = (bid - 2304) * 256 + tid;
    float4 v = *(const float4*)(out_w + (size_t)i * 4);
    union { unsigned long long d; unsigned u[2]; } pk;
    pk.u[0] = cvt_pk_bf16(v.x, v.y);
    pk.u[1] = cvt_pk_bf16(v.z, v.w);
    *(unsigned long long*)(wo + (size_t)i * 4) = pk.d;
  } else {
    int idx = (bid - 2880) * 256 + tid;          // 0..221183 over (h, bs, j)
    int j = idx & 15;
    int hb = idx >> 4;                           // h*1152 + bs
    int h = hb / 1152;
    int bs = hb - h * 1152;
    float p = pos[(size_t)bs * 2 + (j >> 3)];
    float th = p * freqs[h * 8 + (j & 7)];
    float sn, cn;
    __sincosf(th, &sn, &cn);
    trig[idx] = make_float2(cn, sn);
  }
}

// ---------------- MFMA GEMM core (128x128, 4 waves): dbuf + counted vmcnt --------
__device__ __forceinline__ void gemm_bt_lds(const u16* __restrict__ A,
                                            const u16* __restrict__ B,
                                            int K, int m0, int n0, int tid,
                                            u16* ldsA, u16* ldsB,
                                            f32x4 acc[4][4]) {
  int lane = tid & 63;
  int wid = tid >> 6;
  int wm = (wid >> 1) * 64, wn = (wid & 1) * 64;
  int lr = lane & 15, lg = lane >> 4;
  const u16* gA = A + (size_t)(m0 + wid * 32 + (lane >> 3)) * K + (((lane & 7) ^ (lane >> 3)) * 8);
  const u16* gB = B + (size_t)(n0 + wid * 32 + (lane >> 3)) * K + (((lane & 7) ^ (lane >> 3)) * 8);
  u16* dA = ldsA + wid * 2048;
  u16* dB = ldsB + wid * 2048;
  auto STAGE = [&](int buf, int k0) {
    u16* dAb = dA + buf * 8192;
    u16* dBb = dB + buf * 8192;
    #pragma unroll
    for (int is = 0; is < 4; is++) {
      __builtin_amdgcn_global_load_lds(
          (const __attribute__((address_space(1))) unsigned int*)(gA + (size_t)(is * 8) * K + k0),
          (__attribute__((address_space(3))) unsigned int*)(dAb + is * 512),
          16, 0, 0);
      __builtin_amdgcn_global_load_lds(
          (const __attribute__((address_space(1))) unsigned int*)(gB + (size_t)(is * 8) * K + k0),
          (__attribute__((address_space(3))) unsigned int*)(dBb + is * 512),
          16, 0, 0);
    }
  };
  int nt = K >> 6;
  STAGE(0, 0);
  int cur = 0;
  #pragma unroll 1
  for (int t = 0; t < nt; t++) {
    if (t + 1 < nt) {
      STAGE(cur ^ 1, (t + 1) * 64);
      asm volatile("s_waitcnt vmcnt(8)" ::: "memory");
    } else {
      asm volatile("s_waitcnt vmcnt(0)" ::: "memory");
    }
    __builtin_amdgcn_s_barrier();
    __builtin_amdgcn_sched_barrier(0);
    const u16* lA = ldsA + cur * 8192;
    const u16* lB = ldsB + cur * 8192;
    #pragma unroll
    for (int kk = 0; kk < 2; kk++) {
      bf16x8 af[4], bfr[4];
      #pragma unroll
      for (int i = 0; i < 4; i++)
        af[i]  = *(const bf16x8*)&lA[(wm + i * 16 + lr) * 64 + (((lg + 4 * kk) ^ (lr & 7)) * 8)];
      #pragma unroll
      for (int j = 0; j < 4; j++)
        bfr[j] = *(const bf16x8*)&lB[(wn + j * 16 + lr) * 64 + (((lg + 4 * kk) ^ (lr & 7)) * 8)];
      #pragma unroll
      for (int i = 0; i < 4; i++)
        #pragma unroll
        for (int j = 0; j < 4; j++)
          acc[i][j] = __builtin_amdgcn_mfma_f32_16x16x32_bf16(af[i], bfr[j], acc[i][j], 0, 0, 0);
    }
    __builtin_amdgcn_sched_barrier(0);
    __builtin_amdgcn_s_barrier();
    __builtin_amdgcn_sched_barrier(0);
    cur ^= 1;
  }
}

// XCD-chunk swizzle: grid = 8 XCD * 9 m-blocks * NBLK n-blocks (bijective).
__device__ __forceinline__ void swz_tile(int L, int& m0, int& n0) {
  int xcd = L & 7, loc = L >> 3;
  int nblk = loc / 9, mloc = loc - nblk * 9;
  m0 = (xcd * 9 + mloc) * 128;
  n0 = nblk * 128;
}

// ---------------- QKV GEMM (R16 config): 128^2, fused RoPE, coalesced stores ------
__global__ __launch_bounds__(256) void gemm_qkv(const u16* __restrict__ xn,
                                                const u16* __restrict__ wq,
                                                const float2* __restrict__ trig,
                                                const float* __restrict__ scale,
                                                u16* __restrict__ q,
                                                u16* __restrict__ k,
                                                u16* __restrict__ vt) {
  __shared__ u16 smem[32768];              // 64 KB: staging dbuf; reused by epilogue
  u16* ldsA = smem;
  u16* ldsB = smem + 16384;
  f32x4 acc[4][4] = {};
  int tid = threadIdx.x;
  int m0, n0;
  swz_tile(blockIdx.x, m0, n0);
  gemm_bt_lds(xn, wq, CDIM, m0, n0, tid, ldsA, ldsB, acc);
  int lane = tid & 63, wid = tid >> 6;
  int wm = (wid >> 1) * 64, wn = (wid & 1) * 64;
  int lr = lane & 15, rb = (lane >> 4) * 4;
  int part = n0 / CDIM;                    // block-uniform
  int hbase = (n0 - part * CDIM) >> 6;     // block-uniform head base (2 heads/block)
  int nidx_b = m0 / SDIM, rm0 = m0 - nidx_b * SDIM;
  u16* T = smem;                           // [128][136]
  if (part < 2) {
    int h = hbase + (wn >> 6);             // wave-uniform head
    float sq = sqrtf(scale[h]) * (part == 0 ? 1.44269504f : 1.0f);
    const float2* tg = trig + (size_t)h * 1152 * 16;
    #pragma unroll
    for (int i = 0; i < 4; i++)
      #pragma unroll
      for (int r = 0; r < 4; r++) {
        int off = wm + i * 16 + rb + r;    // 0..127; slab never crosses 576
        int sp = rm0 + off;
        int nidx = nidx_b + (sp >= SDIM);
        sp -= (sp >= SDIM) ? SDIM : 0;
        int b = nidx >> 3;
        float2 cssn = tg[((size_t)b * SDIM + sp) * 16 + lr];
        float v0 = acc[i][0][r];
        float v1 = acc[i][1][r];
        float v2 = acc[i][2][r];
        float v3 = acc[i][3][r];
        float ss = v0 * v0 + v1 * v1 + v2 * v2 + v3 * v3;
        ss += __shfl_xor(ss, 1); ss += __shfl_xor(ss, 2);
        ss += __shfl_xor(ss, 4); ss += __shfl_xor(ss, 8);
        float rs = sq * rsqrtf(ss + 1e-6f);
        v0 *= rs; v1 *= rs; v2 *= rs; v3 *= rs;
        float o0 = v0 * cssn.x - v1 * cssn.y;
        float o1 = v1 * cssn.x + v0 * cssn.y;
        u16* trow = T + (size_t)off * 136 + wn + lr;
        trow[0]  = f2bf(o0); trow[16] = f2bf(o1);
        trow[32] = f2bf(v2); trow[48] = f2bf(v3);
      }
    __syncthreads();
    u16* dst = (part == 0) ? q : k;
    #pragma unroll
    for (int c = 0; c < 8; c++) {
      int chunk = c * 256 + tid;           // 2048 chunks of u16x8
      int ml = chunk >> 4, sub = chunk & 15;
      int sp = rm0 + ml;
      int nidx = nidx_b + (sp >= SDIM);
      sp -= (sp >= SDIM) ? SDIM : 0;
      int hl = sub >> 3, e0 = (sub & 7) * 8;
      u16x8 v = *(const u16x8*)&T[(size_t)ml * 136 + sub * 8];
      *(u16x8*)(dst + ((size_t)(nidx * NHEAD + hbase + hl) * SDIM + sp) * EDIM + e0) = v;
    }
  } else {
    #pragma unroll
    for (int i = 0; i < 4; i++)
      #pragma unroll
      for (int j = 0; j < 4; j++)
        #pragma unroll
        for (int r = 0; r < 4; r++)
          T[(size_t)(wn + j * 16 + lr) * 136 + (wm + i * 16 + rb + r)] = f2bf(acc[i][j][r]);
    __syncthreads();
    #pragma unroll
    for (int c = 0; c < 8; c++) {
      int chunk = c * 256 + tid;
      int nl = chunk >> 4, sub = chunk & 15;
      int hl = nl >> 6, e = nl & 63;
      int hw = rm0 + sub * 8;              // 576%8==0: chunk never straddles
      int nidx = nidx_b + (hw >= SDIM);
      hw -= (hw >= SDIM) ? SDIM : 0;
      u16x8 v = *(const u16x8*)&T[(size_t)nl * 136 + sub * 8];
      *(u16x8*)(vt + ((size_t)(nidx * NHEAD + hbase + hl) * EDIM + e) * SDIM + hw) = v;
    }
  }
}

// ---------------- MFMA flash attention v6: triple-buffer, 1 barrier/tile ----------
__global__ __launch_bounds__(256, 2) void attn_mfma(const u16* __restrict__ q,
                                                    const u16* __restrict__ k,
                                                    const u16* __restrict__ vt,
                                                    u16* __restrict__ o) {
  __shared__ u16 kbuf[3][4096];
  __shared__ u16 vbuf[3][4096];
  __shared__ u16 p_lds[4][48][72];
  int L = blockIdx.x;
  int cid = (L & 7) * 72 + (L >> 3);
  int nh_ = cid / 3;
  int qt = cid - nh_ * 3;
  int n = nh_ / NHEAD, h = nh_ - n * NHEAD;
  int tid = threadIdx.x;
  int wid = tid >> 6, lane = tid & 63;
  int lr = lane & 15, lg = lane >> 4;
  int qbase = qt * 192 + wid * 48;

  const u16* qp = q + ((size_t)nh_ * SDIM + qbase) * EDIM;
  bf16x8 qa[3][2];
  #pragma unroll
  for (int f = 0; f < 3; f++) {
    qa[f][0] = *(const bf16x8*)(qp + (size_t)(f * 16 + lr) * EDIM + lg * 8);
    qa[f][1] = *(const bf16x8*)(qp + (size_t)(f * 16 + lr) * EDIM + 32 + lg * 8);
  }
  const u16* kb = k + (size_t)nh_ * SDIM * EDIM;
  const u16* vb = vt + (size_t)nh_ * EDIM * SDIM;

  int srow = wid * 16 + (lane >> 3);
  int schunk = (lane & 7) ^ (lane >> 3);
  auto STAGE = [&](int buf, int s0) {
    #pragma unroll
    for (int is = 0; is < 2; is++) {
      int row = srow + is * 8;
      __builtin_amdgcn_global_load_lds(
          (const __attribute__((address_space(1))) unsigned int*)(kb + (size_t)(s0 + row) * EDIM + schunk * 8),
          (__attribute__((address_space(3))) unsigned int*)(&kbuf[buf][(size_t)(wid * 16 + is * 8 + (lane >> 3)) * 64 + (lane & 7) * 8]),
          16, 0, 0);
      __builtin_amdgcn_global_load_lds(
          (const __attribute__((address_space(1))) unsigned int*)(vb + (size_t)row * SDIM + s0 + schunk * 8),
          (__attribute__((address_space(3))) unsigned int*)(&vbuf[buf][(size_t)(wid * 16 + is * 8 + (lane >> 3)) * 64 + (lane & 7) * 8]),
          16, 0, 0);
    }
  };

  float psum[3] = {0.0f, 0.0f, 0.0f};
  f32x4 oacc[3][4] = {};

  STAGE(0, 0);
  STAGE(1, 64);
  #pragma unroll 1
  for (int kt = 0; kt < 9; kt++) {
    if (kt < 8) {
      asm volatile("s_waitcnt vmcnt(4)" ::: "memory");
    } else {
      asm volatile("s_waitcnt vmcnt(0)" ::: "memory");
    }
    __builtin_amdgcn_s_barrier();
    __builtin_amdgcn_sched_barrier(0);
    if (kt < 7) STAGE((kt + 2) % 3, (kt + 2) * 64);
    const u16* kl = kbuf[kt % 3];
    const u16* vl = vbuf[kt % 3];
    bf16x8 kf[4][2];
    #pragma unroll
    for (int j = 0; j < 4; j++) {
      kf[j][0] = *(const bf16x8*)&kl[(j * 16 + lr) * 64 + ((lg       ^ (lr & 7)) * 8)];
      kf[j][1] = *(const bf16x8*)&kl[(j * 16 + lr) * 64 + (((lg + 4) ^ (lr & 7)) * 8)];
    }
    bf16x8 vf[2][4];
    #pragma unroll
    for (int ks = 0; ks < 2; ks++)
      #pragma unroll
      for (int et = 0; et < 4; et++)
        vf[ks][et] = *(const bf16x8*)&vl[(et * 16 + lr) * 64 + (((ks * 4 + lg) ^ (lr & 7)) * 8)];
    #pragma unroll
    for (int f = 0; f < 3; f++) {
      f32x4 sfr[4] = {};
      __builtin_amdgcn_s_setprio(1);
      #pragma unroll
      for (int j = 0; j < 4; j++) {
        sfr[j] = __builtin_amdgcn_mfma_f32_16x16x32_bf16(kf[j][0], qa[f][0], sfr[j], 0, 0, 0);
        sfr[j] = __builtin_amdgcn_mfma_f32_16x16x32_bf16(kf[j][1], qa[f][1], sfr[j], 0, 0, 0);
      }
      __builtin_amdgcn_s_setprio(0);
      float fs = 0.0f;
      #pragma unroll
      for (int j = 0; j < 4; j++) {
        float p0 = exp2f(sfr[j][0]);
        float p1 = exp2f(sfr[j][1]);
        float p2 = exp2f(sfr[j][2]);
        float p3 = exp2f(sfr[j][3]);
        unsigned w0 = cvt_pk_bf16(p0, p1);
        unsigned w1 = cvt_pk_bf16(p2, p3);
        *(unsigned*)&p_lds[wid][f * 16 + lr][j * 16 + lg * 4]     = w0;
        *(unsigned*)&p_lds[wid][f * 16 + lr][j * 16 + lg * 4 + 2] = w1;
        fs += (p0 + p1) + (p2 + p3);
      }
      psum[f] += fs;
    }
    __builtin_amdgcn_s_setprio(1);
    #pragma unroll
    for (int f = 0; f < 3; f++)
      #pragma unroll
      for (int ks = 0; ks < 2; ks++) {
        bf16x8 pa = *(const bf16x8*)&p_lds[wid][f * 16 + lr][ks * 32 + lg * 8];
        #pragma unroll
        for (int et = 0; et < 4; et++)
          oacc[f][et] = __builtin_amdgcn_mfma_f32_16x16x32_bf16(pa, vf[ks][et], oacc[f][et], 0, 0, 0);
      }
    __builtin_amdgcn_s_setprio(0);
    __builtin_amdgcn_sched_barrier(0);
  }
  u16* ob = o + ((size_t)n * SDIM + qbase) * CDIM + h * EDIM;
  #pragma unroll
  for (int f = 0; f < 3; f++) {
    float s = psum[f];
    s += __shfl_xor(s, 16);
    s += __shfl_xor(s, 32);
    float inv = 1.0f / s;
    #pragma unroll
    for (int r = 0; r < 4; r++) {
      float invr = __shfl(inv, lg * 4 + r);
      #pragma unroll
      for (int et = 0; et < 4; et++)
        ob[(size_t)(f * 16 + lg * 4 + r) * CDIM + et * 16 + lr] = f2bf(oacc[f][et][r] * invr);
    }
  }
}

// ---------------- out projection + skip, COALESCED via LDS transpose ----------------
__global__ __launch_bounds__(256) void gemm_proj(const u16* __restrict__ o,
                                                 const u16* __restrict__ wo,
                                                 const float* __restrict__ x,
                                                 float* __restrict__ out) {
  __shared__ __align__(16) char smem[128 * 132 * 4];
  u16* ldsA = (u16*)smem;
  u16* ldsB = (u16*)smem + 16384;
  f32x4 acc[4][4] = {};
  int tid = threadIdx.x;
  int m0, n0;
  swz_tile(blockIdx.x, m0, n0);
  gemm_bt_lds(o, wo, CDIM, m0, n0, tid, ldsA, ldsB, acc);
  int lane = tid & 63, wid = tid >> 6;
  int wm = (wid >> 1) * 64, wn = (wid & 1) * 64;
  int lr = lane & 15, rb = (lane >> 4) * 4;
  int nidx_b = m0 / SDIM, rm0 = m0 - nidx_b * SDIM;
  float* T = (float*)smem;
  #pragma unroll
  for (int i = 0; i < 4; i++)
    #pragma unroll
    for (int j = 0; j < 4; j++)
      #pragma unroll
      for (int r = 0; r < 4; r++)
        T[(size_t)(wn + j * 16 + lr) * 132 + (wm + i * 16 + rb + r)] = acc[i][j][r];
  __syncthreads();
  #pragma unroll
  for (int c = 0; c < 16; c++) {
    int chunk = c * 256 + tid;
    int nl = chunk >> 5, sub = chunk & 31;
    int hw = rm0 + sub * 4;
    int nidx = nidx_b + (hw >= SDIM);
    hw -= (hw >= SDIM) ? SDIM : 0;
    int b = nidx >> 3, t = nidx & 7;
    int jj = n0 + nl;
    size_t oi = ((size_t)(b * CDIM + jj) * TDIM + t) * SDIM + hw;
    float4 xv = *(const float4*)&x[oi];
    float4 tv = *(const float4*)&T[(size_t)nl * 132 + sub * 4];
    float4 ov;
    ov.x = tv.x + xv.x; ov.y = tv.y + xv.y;
    ov.z = tv.z + xv.z; ov.w = tv.w + xv.w;
    *(float4*)&out[oi] = ov;
  }
}

extern "C" void kernel_launch(void* const* d_in, const int* in_sizes, int n_in,
                              void* d_out, int out_size, void* d_ws, size_t ws_size,
                              hipStream_t stream) {
  const float* x      = (const float*)d_in[0];
  const float* pos    = (const float*)d_in[1];
  const float* cond   = (const float*)d_in[2];
  const float* norm_w = (const float*)d_in[3];
  const float* qkv_w  = (const float*)d_in[4];
  const float* scale  = (const float*)d_in[5];
  const float* out_w  = (const float*)d_in[6];
  const float* freqs  = (const float*)d_in[7];
  float* out = (float*)d_out;

  char* ws = (char*)d_ws;
  size_t off = 0;
  auto alloc = [&](size_t bytes) -> char* {
    char* p = ws + off;
    off = (off + bytes + 255) & ~(size_t)255;
    return p;
  };
  float* cs   = (float*)alloc(2 * CDIM * sizeof(float));
  u16* wq     = (u16*)alloc((size_t)QKVN * CDIM * 2);
  u16* wo     = (u16*)alloc((size_t)CDIM * CDIM * 2);
  u16* xn     = (u16*)alloc((size_t)MDIM * CDIM * 2);
  u16* qb     = (u16*)alloc((size_t)MDIM * CDIM * 2);
  u16* kb     = (u16*)alloc((size_t)MDIM * CDIM * 2);
  u16* vt     = (u16*)alloc((size_t)MDIM * CDIM * 2);
  u16* ob     = (u16*)alloc((size_t)MDIM * CDIM * 2);
  float2* trg = (float2*)alloc((size_t)NHEAD * 2 * SDIM * 16 * sizeof(float2));

  cs_kernel<<<dim3(24), dim3(256), 0, stream>>>(cond, norm_w, cs);
  norm_prep_kernel<<<dim3(3744), dim3(256), 0, stream>>>(x, cs, xn, qkv_w, wq,
                                                         out_w, wo, pos, freqs, trg);
  gemm_qkv<<<dim3(8 * 9 * (QKVN / 128)), dim3(256), 0, stream>>>(xn, wq, trg, scale, qb, kb, vt);
  attn_mfma<<<dim3(576), dim3(256), 0, stream>>>(qb, kb, vt, ob);
  gemm_proj<<<dim3(8 * 9 * (CDIM / 128)), dim3(256), 0, stream>>>(ob, wo, x, out);
}